// Round 16
// baseline (399.975 us; speedup 1.0000x reference)
//
#include <hip/hip_runtime.h>
#include <math.h>

#define NN 4096

typedef __bf16 bf16x8 __attribute__((ext_vector_type(8)));
typedef float  f32x4  __attribute__((ext_vector_type(4)));

static __device__ __forceinline__ unsigned enc_f(float f){
    unsigned u = __float_as_uint(f);
    return (u & 0x80000000u) ? ~u : (u | 0x80000000u);
}
static __device__ __forceinline__ float dec_f(unsigned u){
    unsigned b = (u & 0x80000000u) ? (u & 0x7fffffffu) : ~u;
    return __uint_as_float(b);
}
static __device__ __forceinline__ unsigned long long shflx_u64(unsigned long long v, int m){
    unsigned lo = __shfl_xor((unsigned)(v & 0xffffffffu), m, 64);
    unsigned hi = __shfl_xor((unsigned)(v >> 32), m, 64);
    return ((unsigned long long)hi << 32) | lo;
}

// ---------- phase 1: x0 assembly + packed pos/Ot + column sums ----------
__global__ void k_prep(const float* __restrict__ dx1, const float* __restrict__ dx2,
                       const float* __restrict__ Wk, const float* __restrict__ bk,
                       float* __restrict__ x0, float* __restrict__ colsum,
                       float2* __restrict__ pos, float4* __restrict__ otp){
    int n = blockIdx.x*blockDim.x + threadIdx.x;
    if (n >= NN) return;
    float wk[8];
    #pragma unroll
    for (int j=0;j<8;j++) wk[j] = Wk[j];
    float bkv = bk[0];
    float4 d1 = *(const float4*)&dx1[n*4];
    pos[n] = make_float2(d1.x, d1.y);
    #pragma unroll
    for (int c=0;c<4;c++) x0[n*8+c] = (&d1.x)[c];
    float4 ot;
    #pragma unroll
    for (int c=0;c<4;c++){
        float acc = bkv;
        #pragma unroll
        for (int j=0;j<8;j++) acc += dx2[(n*8+j)*4+c]*wk[j];
        x0[n*8+4+c] = acc;
        (&ot.x)[c] = acc;
        atomicAdd(&colsum[c], acc);
    }
    otp[n] = ot;
}

// ---------- phase 1b: Ty[j] = column-conv kernel applied to Ot ----------
__global__ void k_ty(const float* __restrict__ x0,
        const float* __restrict__ Wcy3, const float* __restrict__ Wcy5, const float* __restrict__ Wcy9,
        float* __restrict__ Ty){
    int j = blockIdx.x*256 + threadIdx.x;
    if (j >= NN) return;
    float Cy[9];
    #pragma unroll
    for (int o=-4;o<=4;o++){
        float c = Wcy9[o+4];
        if (o>=-2 && o<=2) c += Wcy5[o+2];
        if (o>=-1 && o<=1) c += Wcy3[o+1];
        Cy[o+4] = c;
    }
    float4 acc = {0,0,0,0};
    #pragma unroll
    for (int o=-4;o<=4;o++){
        int jj = j - o;
        if ((unsigned)jj < NN){
            float4 ot = *(const float4*)&x0[jj*8+4];
            float c = Cy[o+4];
            acc.x += c*ot.x; acc.y += c*ot.y; acc.z += c*ot.z; acc.w += c*ot.w;
        }
    }
    *(float4*)&Ty[j*4] = acc;
}

// ---------- phase 2: two-pass knn ----------
#define KCAP 192
__global__ __launch_bounds__(256) void k_dist(const float2* __restrict__ pos,
        const float4* __restrict__ otp,
        float* __restrict__ maxd, int* __restrict__ nbr,
        int* __restrict__ cnt3, int* __restrict__ cnt5, int* __restrict__ cnt9,
        float* __restrict__ dOt){
    __shared__ unsigned long long cbuf[4][KCAP];
    int tid = threadIdx.x;
    int w = tid >> 6, lane = tid & 63;
    int i = blockIdx.x*4 + w;
    float2 pi = pos[i];

    float lmax = 0.f, lmin = INFINITY;
    float4 dacc = {0,0,0,0};
    for (int t=0;t<64;t++){
        int j = (t<<6) | lane;
        float2 p = pos[j];
        float dx = pi.x - p.x, dy = pi.y - p.y;
        float d = sqrtf(dx*dx + dy*dy);
        lmax = fmaxf(lmax, d);
        float4 otj = otp[j];
        dacc.x += d*otj.x; dacc.y += d*otj.y; dacc.z += d*otj.z; dacc.w += d*otj.w;
        if (j != i) lmin = fminf(lmin, d);
    }
    #pragma unroll
    for (int m=1;m<64;m<<=1){
        lmax = fmaxf(lmax, __shfl_xor(lmax, m, 64));
        dacc.x += __shfl_xor(dacc.x, m, 64);
        dacc.y += __shfl_xor(dacc.y, m, 64);
        dacc.z += __shfl_xor(dacc.z, m, 64);
        dacc.w += __shfl_xor(dacc.w, m, 64);
    }
    if (lane==0){
        maxd[i] = lmax;
        *(float4*)&dOt[i*4] = dacc;
    }
    float v = lmin, T = 0.f;
    #pragma unroll
    for (int r=0;r<9;r++){
        float m = v;
        #pragma unroll
        for (int s=1;s<64;s<<=1) m = fminf(m, __shfl_xor(m, s, 64));
        T = m;
        if (v == m) v = INFINITY;
    }

    int base = 0;
    for (int t=0;t<64;t++){
        int j = (t<<6) | lane;
        float2 p = pos[j];
        float dx = pi.x - p.x, dy = pi.y - p.y;
        float d = sqrtf(dx*dx + dy*dy);
        bool pass = (j != i) && (d <= T);
        unsigned long long b = __ballot(pass);
        if (b){
            int pre = __popcll(b & ((1ull<<lane)-1ull));
            int idx = base + pre;
            if (pass && idx < KCAP)
                cbuf[w][idx] = ((unsigned long long)__float_as_uint(d) << 32) | (unsigned)j;
            base += __popcll(b);
        }
    }
    int M = base < KCAP ? base : KCAP;

    unsigned long long c0 = (lane      < M) ? cbuf[w][lane]      : ~0ULL;
    unsigned long long c1 = (lane+64   < M) ? cbuf[w][lane+64]   : ~0ULL;
    unsigned long long c2 = (lane+128  < M) ? cbuf[w][lane+128]  : ~0ULL;
    for (int r=0;r<9;r++){
        unsigned long long mv = c0 < c1 ? c0 : c1;
        mv = mv < c2 ? mv : c2;
        #pragma unroll
        for (int s=1;s<64;s<<=1){
            unsigned long long o = shflx_u64(mv, s);
            if (o < mv) mv = o;
        }
        if (c0 == mv) c0 = ~0ULL;
        else if (c1 == mv) c1 = ~0ULL;
        else if (c2 == mv) c2 = ~0ULL;
        if (lane == 0){
            int j = (int)(mv & 0xffffffffu);
            nbr[i*9+r] = j;
            atomicAdd(&cnt9[j], 1);
            if (r<5) atomicAdd(&cnt5[j], 1);
            if (r<3) atomicAdd(&cnt3[j], 1);
        }
    }
}

// ---------- phase 2b: CSR offsets (exclusive scan) + dinv ----------
__global__ __launch_bounds__(256) void k_scan(const int* __restrict__ cnt3,
        const int* __restrict__ cnt5, const int* __restrict__ cnt9,
        int* __restrict__ offc, float* __restrict__ dinvc){
    __shared__ int part[256];
    int tid = threadIdx.x;
    for (int g=0; g<3; g++){
        const int* cp = g==0?cnt3:(g==1?cnt5:cnt9);
        int base = tid*16;
        int loc[16]; int s=0;
        #pragma unroll
        for (int q=0;q<16;q++){ loc[q]=s; s += cp[base+q]; }
        part[tid]=s; __syncthreads();
        for (int d=1; d<256; d<<=1){
            int v = (tid>=d) ? part[tid-d] : 0;
            __syncthreads();
            part[tid] += v;
            __syncthreads();
        }
        int pre = (tid==0) ? 0 : part[tid-1];
        #pragma unroll
        for (int q=0;q<16;q++){
            offc[g*NN + base + q]  = pre + loc[q];
            dinvc[g*NN + base + q] = rsqrtf((float)cp[base+q] + 1.f);
        }
        __syncthreads();
    }
}

// ---------- phase 2c: fill reverse-edge lists ----------
__global__ void k_fill(const int* __restrict__ nbr, const int* __restrict__ offc,
        int* __restrict__ cur, int* __restrict__ rev){
    int i = blockIdx.x*256 + threadIdx.x;
    if (i >= NN) return;
    #pragma unroll
    for (int t=0;t<9;t++){
        int j = nbr[i*9+t];
        int gmin = t<3 ? 0 : (t<5 ? 1 : 2);
        for (int g=gmin; g<3; g++){
            int pos = atomicAdd(&cur[g*NN+j], 1);
            int rb = (g==0) ? 0 : (g==1 ? NN*3 : NN*8);
            rev[rb + offc[g*NN+j] + pos] = i;
        }
    }
}

// ---------- phase 3: GCN layer-1 input transform ----------
__global__ void k_y1(const float* __restrict__ x0, const float* __restrict__ Wg1,
                     float* __restrict__ xw){
    int idx = blockIdx.x*256 + threadIdx.x;
    if (idx >= NN*64) return;
    int n = idx>>6, c = idx&63;
    float acc = 0.f;
    #pragma unroll
    for (int k=0;k<8;k++) acc += x0[n*8+k]*Wg1[k*64+c];
    xw[idx] = acc;
}

// ---------- phase 3b: gather layer-1 + relu + layer-2 matmul ----------
__global__ __launch_bounds__(256) void k_h1y2(const float* __restrict__ xw,
        const int* __restrict__ offc,
        const int* __restrict__ cnt3, const int* __restrict__ cnt5, const int* __restrict__ cnt9,
        const int* __restrict__ rev, const float* __restrict__ dinvc,
        const float* __restrict__ bg1, const float* __restrict__ Wg2,
        float* __restrict__ y2){
    __shared__ float h1s[12][64];
    int n0 = blockIdx.x*4, tid = threadIdx.x;
    for (int s=tid; s<768; s+=256){
        int p = s>>6, k = s&63, g = p>>2, n = n0+(p&3);
        const int* cp = g==0?cnt3:(g==1?cnt5:cnt9);
        int rb = (g==0) ? 0 : (g==1 ? NN*3 : NN*8);
        int cnt = cp[n];
        int o = rb + offc[g*NN+n];
        float dv = dinvc[g*NN+n];
        float srow = dv*xw[n*64+k];
        for (int e=0;e<cnt;e++){
            int i = rev[o+e];
            srow += dinvc[g*NN+i]*xw[i*64+k];
        }
        float v = dv*srow + bg1[k];
        h1s[p][k] = v>0.f ? v : 0.f;
    }
    __syncthreads();
    int c = tid & 127, ph = tid>>7;
    float a6[6] = {0,0,0,0,0,0};
    for (int k=0;k<64;k++){
        float w = Wg2[k*128+c];
        #pragma unroll
        for (int q=0;q<6;q++) a6[q] += h1s[q*2+ph][k]*w;
    }
    #pragma unroll
    for (int q=0;q<6;q++){
        int p = q*2+ph, g = p>>2, n = n0+(p&3);
        float dv = dinvc[g*NN+n];
        y2[(size_t)g*NN*128 + (size_t)n*128 + c] = dv*a6[q];
    }
}

// ---------- phase 3c: gather layer-2 + bias + log_softmax ----------
__global__ __launch_bounds__(128) void k_fin(const float* __restrict__ y2,
        const int* __restrict__ offc,
        const int* __restrict__ cnt3, const int* __restrict__ cnt5, const int* __restrict__ cnt9,
        const int* __restrict__ rev, const float* __restrict__ dinvc,
        const float* __restrict__ bg2, float* __restrict__ emb){
    __shared__ float sm[2], ss[2];
    int b = blockIdx.x;
    int n = b & (NN-1), g = b >> 12;
    const int* cp = g==0?cnt3:(g==1?cnt5:cnt9);
    int rb = (g==0) ? 0 : (g==1 ? NN*3 : NN*8);
    int cnt = cp[n];
    int o = rb + offc[g*NN+n];
    float dv = dinvc[g*NN+n];
    int c = threadIdx.x;
    const float* yg = y2 + (size_t)g*NN*128;
    float s = yg[(size_t)n*128 + c];
    for (int e=0;e<cnt;e++){
        int i = rev[o+e];
        s += yg[(size_t)i*128 + c];
    }
    float v = dv*s + bg2[c];
    float m = v;
    #pragma unroll
    for (int st=1;st<64;st<<=1) m = fmaxf(m, __shfl_xor(m, st, 64));
    if ((c&63)==0) sm[c>>6] = m;
    __syncthreads();
    m = fmaxf(sm[0], sm[1]);
    float e = expf(v - m);
    float t = e;
    #pragma unroll
    for (int st=1;st<64;st<<=1) t += __shfl_xor(t, st, 64);
    if ((c&63)==0) ss[c>>6] = t;
    __syncthreads();
    t = ss[0]+ss[1];
    emb[n*384 + g*128 + c] = v - m - logf(t);
}

// ---------- phase 4: q/k projections -> bf16 hi/lo split ----------
__global__ __launch_bounds__(256) void k_qk(const float* __restrict__ emb,
        const float* __restrict__ Wq, const float* __restrict__ bq,
        const float* __restrict__ Wkey, const float* __restrict__ bkey,
        __bf16* __restrict__ qh, __bf16* __restrict__ ql,
        __bf16* __restrict__ kh, __bf16* __restrict__ kl){
    __shared__ float es[8][384];
    int n0 = blockIdx.x*8;
    int tid = threadIdx.x;
    for (int idx=tid; idx<8*384; idx+=256){
        int m = idx/384, k = idx%384;
        es[m][k] = emb[(n0+m)*384+k];
    }
    __syncthreads();
    int c = tid & 127;
    int sel = tid >> 7;
    const float* W = sel ? Wkey : Wq;
    float b = sel ? bkey[c] : bq[c];
    float acc[8];
    #pragma unroll
    for (int m=0;m<8;m++) acc[m]=b;
    for (int k=0;k<384;k++){
        float w = W[k*128+c];
        #pragma unroll
        for (int m=0;m<8;m++) acc[m] += es[m][k]*w;
    }
    __bf16* oh = sel ? kh : qh;
    __bf16* ol = sel ? kl : ql;
    #pragma unroll
    for (int m=0;m<8;m++){
        float v = acc[m];
        __bf16 h = (__bf16)v;
        oh[(size_t)(n0+m)*128+c] = h;
        ol[(size_t)(n0+m)*128+c] = (__bf16)(v - (float)h);
    }
}

// ---------- phase 5: row max/min of q@k^T via MFMA (NO scores materialization) ----------
// 64x32 wave tile, no stores at all -> isolates whether the ~50us wall was the
// scores write path. Row max/min from exact f32 accumulators + enc atomics.
__global__ __launch_bounds__(256) void k_qkmm(
        const __bf16* __restrict__ qh, const __bf16* __restrict__ ql,
        const __bf16* __restrict__ kh, const __bf16* __restrict__ kl,
        unsigned* __restrict__ rowmaxenc, unsigned* __restrict__ rowminenc){
    int bx = blockIdx.x & 63;        // col block (64 cols)
    int by = blockIdx.x >> 6;        // row block (128 rows)
    int tid = threadIdx.x;
    int w = tid >> 6, lane = tid & 63;
    int li = lane & 15, g = lane >> 4;
    int r0 = by*128 + (w>>1)*64;
    int c0 = bx*64  + (w&1)*32;

    f32x4 acc[4][2] = {};
    for (int ks=0; ks<4; ++ks){
        int kofs = ks*32 + g*8;
        bf16x8 ah[4], al[4], bh[2], bl[2];
        #pragma unroll
        for (int f=0; f<4; ++f){
            ah[f] = *(const bf16x8*)&qh[(size_t)(r0+f*16+li)*128 + kofs];
            al[f] = *(const bf16x8*)&ql[(size_t)(r0+f*16+li)*128 + kofs];
        }
        #pragma unroll
        for (int f=0; f<2; ++f){
            bh[f] = *(const bf16x8*)&kh[(size_t)(c0+f*16+li)*128 + kofs];
            bl[f] = *(const bf16x8*)&kl[(size_t)(c0+f*16+li)*128 + kofs];
        }
        #pragma unroll
        for (int fr=0; fr<4; ++fr){
            #pragma unroll
            for (int fc=0; fc<2; ++fc){
                acc[fr][fc] = __builtin_amdgcn_mfma_f32_16x16x32_bf16(ah[fr], bh[fc], acc[fr][fc], 0, 0, 0);
                acc[fr][fc] = __builtin_amdgcn_mfma_f32_16x16x32_bf16(ah[fr], bl[fc], acc[fr][fc], 0, 0, 0);
                acc[fr][fc] = __builtin_amdgcn_mfma_f32_16x16x32_bf16(al[fr], bh[fc], acc[fr][fc], 0, 0, 0);
            }
        }
    }
    #pragma unroll
    for (int fr=0; fr<4; ++fr){
        #pragma unroll
        for (int r=0; r<4; ++r){
            int row = r0 + fr*16 + g*4 + r;
            float mx = fmaxf(acc[fr][0][r], acc[fr][1][r]);
            float mn = fminf(acc[fr][0][r], acc[fr][1][r]);
            #pragma unroll
            for (int s=1; s<16; s<<=1){
                mx = fmaxf(mx, __shfl_xor(mx, s, 64));
                mn = fminf(mn, __shfl_xor(mn, s, 64));
            }
            if (li == 0){
                atomicMax(&rowmaxenc[row], enc_f(mx));
                atomicMin(&rowminenc[row], enc_f(mn));
            }
        }
    }
}

// ---------- phase 5b: invr = 1/rowmax ----------
__global__ void k_invr(const unsigned* __restrict__ rowmaxenc, float* __restrict__ invr){
    int i = blockIdx.x*256 + threadIdx.x;
    if (i >= NN) return;
    invr[i] = 1.f/dec_f(rowmaxenc[i]);
}

// ---------- phase 6: fused recompute + conv min/max (56x56 output tile / block) ----------
// Recomputes the 64x64 score tile (output + 4 halo) in registers via MFMA,
// scales by invr, zero-pads OOR into a 17KB LDS tile, conv min/max from LDS.
// Scores never touch global memory.
__global__ __launch_bounds__(256) void k_convf(
        const __bf16* __restrict__ qh, const __bf16* __restrict__ ql,
        const __bf16* __restrict__ kh, const __bf16* __restrict__ kl,
        const float* __restrict__ invr,
        const float* __restrict__ Wcy3, const float* __restrict__ Wcx3,
        const float* __restrict__ Wcy5, const float* __restrict__ Wcx5,
        const float* __restrict__ Wcy9, const float* __restrict__ Wcx9,
        const float* __restrict__ bcy3, const float* __restrict__ bcx3,
        const float* __restrict__ bcy5, const float* __restrict__ bcx5,
        const float* __restrict__ bcy9, const float* __restrict__ bcx9,
        float* __restrict__ mnmx){
    __shared__ float As[64][68];
    __shared__ float smn[4], smx[4];
    int bx = blockIdx.x, by = blockIdx.y;
    int i0 = by*56 - 4;      // tile origin (global row), may be <0
    int j0 = bx*56 - 4;
    int tid = threadIdx.x;
    int w = tid >> 6, lane = tid & 63;
    int li = lane & 15, g = lane >> 4;

    // wave w computes cols j0 + w*16 .. +15, all 64 rows
    f32x4 acc[4] = {};
    {
        int col = j0 + w*16 + li;
        int colc = col < 0 ? 0 : (col > NN-1 ? NN-1 : col);
        for (int ks=0; ks<4; ++ks){
            int kofs = ks*32 + g*8;
            bf16x8 ah[4], al[4], bh, bl;
            #pragma unroll
            for (int f=0; f<4; ++f){
                int row = i0 + f*16 + li;
                int rowc = row < 0 ? 0 : (row > NN-1 ? NN-1 : row);
                ah[f] = *(const bf16x8*)&qh[(size_t)rowc*128 + kofs];
                al[f] = *(const bf16x8*)&ql[(size_t)rowc*128 + kofs];
            }
            bh = *(const bf16x8*)&kh[(size_t)colc*128 + kofs];
            bl = *(const bf16x8*)&kl[(size_t)colc*128 + kofs];
            #pragma unroll
            for (int fr=0; fr<4; ++fr){
                acc[fr] = __builtin_amdgcn_mfma_f32_16x16x32_bf16(ah[fr], bh, acc[fr], 0, 0, 0);
                acc[fr] = __builtin_amdgcn_mfma_f32_16x16x32_bf16(ah[fr], bl, acc[fr], 0, 0, 0);
                acc[fr] = __builtin_amdgcn_mfma_f32_16x16x32_bf16(al[fr], bh, acc[fr], 0, 0, 0);
            }
        }
    }
    // write A = scores*invr to LDS, zero-pad out-of-range
    {
        int gcol = j0 + w*16 + li;
        bool cok = (unsigned)gcol < NN;
        #pragma unroll
        for (int fr=0; fr<4; ++fr){
            #pragma unroll
            for (int r=0; r<4; ++r){
                int lr = fr*16 + g*4 + r;
                int grow = i0 + lr;
                float v = 0.f;
                if (cok && (unsigned)grow < NN) v = acc[fr][r] * invr[grow];
                As[lr][w*16 + li] = v;
            }
        }
    }
    __syncthreads();

    float wy3[3],wx3[3],wy5[5],wx5[5],wy9[9],wx9[9];
    #pragma unroll
    for (int t=0;t<3;t++){ wy3[t]=Wcy3[t]; wx3[t]=Wcx3[t]; }
    #pragma unroll
    for (int t=0;t<5;t++){ wy5[t]=Wcy5[t]; wx5[t]=Wcx5[t]; }
    #pragma unroll
    for (int t=0;t<9;t++){ wy9[t]=Wcy9[t]; wx9[t]=Wcx9[t]; }
    float bc3 = bcy3[0]+bcx3[0];
    float bc5 = bcy5[0]+bcx5[0];
    float bc9 = bcy9[0]+bcx9[0];

    float mn = INFINITY, mx = -INFINITY;
    for (int idx = tid; idx < 56*56; idx += 256){
        int r = (idx/56) + 4, c = (idx%56) + 4;
        int grow = i0 + r, gcol = j0 + c;
        if (grow < NN && gcol < NN){
            float cx9=0.f, cx5=0.f, cx3=0.f;
            #pragma unroll
            for (int u=0;u<9;++u){
                float rv = As[r-4+u][c];
                cx9 += rv*wx9[u];
                if (u>=2 && u<=6) cx5 += rv*wx5[u-2];
                if (u>=3 && u<=5) cx3 += rv*wx3[u-3];
            }
            float cy9=0.f, cy5=0.f, cy3=0.f;
            #pragma unroll
            for (int u=0;u<9;++u){
                float cv = As[r][c-4+u];
                cy9 += cv*wy9[u];
                if (u>=2 && u<=6) cy5 += cv*wy5[u-2];
                if (u>=3 && u<=5) cy3 += cv*wy3[u-3];
            }
            float c3v = cy3+cx3+bc3, c5v = cy5+cx5+bc5, c9v = cy9+cx9+bc9;
            mn = fminf(mn, fminf(fminf(c3v,c5v),c9v));
            mx = fmaxf(mx, fmaxf(fmaxf(c3v,c5v),c9v));
        }
    }
    #pragma unroll
    for (int m=1; m<64; m<<=1){
        mn = fminf(mn, __shfl_xor(mn, m, 64));
        mx = fmaxf(mx, __shfl_xor(mx, m, 64));
    }
    if (lane == 0){ smn[w] = mn; smx[w] = mx; }
    __syncthreads();
    if (tid == 0){
        float a0 = fminf(fminf(smn[0],smn[1]), fminf(smn[2],smn[3]));
        float b0 = fmaxf(fmaxf(smx[0],smx[1]), fmaxf(smx[2],smx[3]));
        int bid = by*74 + bx;
        mnmx[bid] = a0;
        mnmx[5632 + bid] = b0;
    }
}

// ---------- phase 6b: kOt[d][0:4]=sum_j k[j][d]*Ot[j], [4:8]=...*Ty[j] ----------
__global__ __launch_bounds__(256) void k_kot(const __bf16* __restrict__ kh, const __bf16* __restrict__ kl,
        const float* __restrict__ x0, const float* __restrict__ Ty,
        float* __restrict__ kOt){
    __shared__ float red[256][8];
    int d = blockIdx.x, tid = threadIdx.x;
    float a[8] = {0,0,0,0,0,0,0,0};
    for (int j = tid; j < NN; j += 256){
        float kv = (float)kh[(size_t)j*128 + d] + (float)kl[(size_t)j*128 + d];
        float4 ot = *(const float4*)&x0[j*8+4];
        float4 ty = *(const float4*)&Ty[j*4];
        a[0] += kv*ot.x; a[1] += kv*ot.y; a[2] += kv*ot.z; a[3] += kv*ot.w;
        a[4] += kv*ty.x; a[5] += kv*ty.y; a[6] += kv*ty.z; a[7] += kv*ty.w;
    }
    #pragma unroll
    for (int q=0;q<8;q++) red[tid][q] = a[q];
    __syncthreads();
    for (int s=128; s>0; s>>=1){
        if (tid < s){
            #pragma unroll
            for (int q=0;q<8;q++) red[tid][q] += red[tid+s][q];
        }
        __syncthreads();
    }
    if (tid < 8) kOt[d*8 + tid] = red[0][tid];
}

// ---------- phase 6c: ASd = invr*(q@kOt), Bv from q@kTy + closed-form ----------
__global__ __launch_bounds__(256) void k_asd(
        const __bf16* __restrict__ qh, const __bf16* __restrict__ ql,
        const float* __restrict__ kOt,
        const float* __restrict__ invr, const float* __restrict__ maxd,
        const float* __restrict__ dOt, const float* __restrict__ colsum,
        const float* __restrict__ bcy3, const float* __restrict__ bcx3,
        const float* __restrict__ bcy5, const float* __restrict__ bcx5,
        const float* __restrict__ bcy9, const float* __restrict__ bcx9,
        float* __restrict__ ASdot, float* __restrict__ Bv){
    __shared__ float kst[128*8];
    int tid = threadIdx.x;
    for (int s = tid; s < 1024; s += 256) kst[s] = kOt[s];
    __syncthreads();
    int lane = tid & 63, r = tid >> 6;
    int i = blockIdx.x*4 + r;
    float a[8] = {0,0,0,0,0,0,0,0};
    #pragma unroll
    for (int dd=0; dd<2; ++dd){
        int d = lane + dd*64;
        float qv = (float)qh[(size_t)i*128 + d] + (float)ql[(size_t)i*128 + d];
        #pragma unroll
        for (int q=0;q<8;q++) a[q] += qv * kst[d*8+q];
    }
    #pragma unroll
    for (int m=1; m<64; m<<=1){
        #pragma unroll
        for (int q=0;q<8;q++) a[q] += __shfl_xor(a[q], m, 64);
    }
    if (lane == 0){
        float iv = invr[i];
        float imv = 1.f/maxd[i];
        float bcsum = bcy3[0]+bcx3[0]+bcy5[0]+bcx5[0]+bcy9[0]+bcx9[0];
        float k = 1.f + bcsum;
        float4 cs = *(const float4*)colsum;
        float4 dv = *(const float4*)&dOt[i*4];
        float4 pa = {iv*a[0], iv*a[1], iv*a[2], iv*a[3]};
        float4 b;
        b.x = cs.x*k - imv*dv.x + iv*a[4];
        b.y = cs.y*k - imv*dv.y + iv*a[5];
        b.z = cs.z*k - imv*dv.z + iv*a[6];
        b.w = cs.w*k - imv*dv.w + iv*a[7];
        *(float4*)&ASdot[i*4] = pa;
        *(float4*)&Bv[i*4]    = b;
    }
}

// ---------- phase 6d: global min/max = conv blocks U A-range U {0,1} ----------
__global__ __launch_bounds__(256) void k_gmm(const float* __restrict__ mnmx,
        const unsigned* __restrict__ rowminenc, const unsigned* __restrict__ rowmaxenc,
        float* __restrict__ gmm){
    __shared__ float smn[256], smx[256];
    int tid = threadIdx.x;
    float mn = 0.f, mx = 1.f;   // oushi range is exactly [0,1]
    for (int i=tid; i<NN; i+=256){
        float rmx = dec_f(rowmaxenc[i]);
        float q = dec_f(rowminenc[i]) / rmx;
        mn = fminf(mn, fminf(1.f, q));
        mx = fmaxf(mx, fmaxf(1.f, q));
    }
    for (int b=tid; b<5476; b+=256){   // 74 x 74 blocks
        mn = fminf(mn, mnmx[b]);
        mx = fmaxf(mx, mnmx[5632+b]);
    }
    smn[tid]=mn; smx[tid]=mx; __syncthreads();
    for (int s=128;s>0;s>>=1){
        if (tid<s){ smn[tid]=fminf(smn[tid],smn[tid+s]); smx[tid]=fmaxf(smx[tid],smx[tid+s]); }
        __syncthreads();
    }
    if (tid==0){ gmm[0]=smn[0]; gmm[1]=smx[0]; }
}

// ---------- phase 7a: row-conv of ASdot + affine -> hfin ----------
__global__ void k_hfin(const float* __restrict__ ASdot, const float* __restrict__ Bv,
        const float* __restrict__ Wcx3, const float* __restrict__ Wcx5, const float* __restrict__ Wcx9,
        const float* __restrict__ gmm, const float* __restrict__ colsum,
        float* __restrict__ hfin){
    int i = blockIdx.x*256 + threadIdx.x;
    if (i >= NN) return;
    float Cx[9];
    #pragma unroll
    for (int o=-4;o<=4;o++){
        float c = Wcx9[o+4];
        if (o>=-2 && o<=2) c += Wcx5[o+2];
        if (o>=-1 && o<=1) c += Wcx3[o+1];
        Cx[o+4] = c;
    }
    float4 h = *(const float4*)&Bv[i*4];
    float4 a0 = *(const float4*)&ASdot[i*4];
    h.x += a0.x; h.y += a0.y; h.z += a0.z; h.w += a0.w;
    #pragma unroll
    for (int o=-4;o<=4;o++){
        int r = i + o;
        if ((unsigned)r < NN){
            float4 av = *(const float4*)&ASdot[r*4];
            float c = Cx[o+4];
            h.x += c*av.x; h.y += c*av.y; h.z += c*av.z; h.w += c*av.w;
        }
    }
    float mnv = gmm[0], mxv = gmm[1];
    float s = 1.f/(mxv-mnv), oa = -mnv*s;
    float4 cs = *(const float4*)colsum;
    float4 out;
    out.x = s*h.x + 5.f*oa*cs.x;
    out.y = s*h.y + 5.f*oa*cs.y;
    out.z = s*h.z + 5.f*oa*cs.z;
    out.w = s*h.w + 5.f*oa*cs.w;
    *(float4*)&hfin[i*4] = out;
}

// ---------- phase 7b: MLP head (barrier-free epilogue) ----------
__global__ __launch_bounds__(256) void k_mlp(const float* __restrict__ hfin,
        const float* __restrict__ Woff, const float* __restrict__ boff, const float* __restrict__ pw,
        const float* __restrict__ Wf1, const float* __restrict__ bf1,
        const float* __restrict__ Wf2, const float* __restrict__ bf2,
        const float* __restrict__ Wf3, const float* __restrict__ bf3,
        float* __restrict__ out){
    __shared__ float h1[8][128];
    __shared__ float h2[8][256];
    __shared__ float h3[8][256];
    int n0 = blockIdx.x*8, tid = threadIdx.x;
    float p = pw[0];
    {
        int c = tid & 127, mb = (tid>>7)*4;
        #pragma unroll
        for (int mm=0; mm<4; mm++){
            int m = mb+mm;
            float v = boff[c];
            #pragma unroll
            for (int k=0;k<4;k++) v += hfin[(n0+m)*4+k]*Woff[k*128+c];
            h1[m][c] = v>0.f ? v : p*v;
        }
    }
    __syncthreads();
    {
        int c = tid;
        float acc[8];
        #pragma unroll
        for (int m=0;m<8;m++) acc[m] = bf1[c];
        for (int k=0;k<128;k++){
            float w = Wf1[k*256+c];
            #pragma unroll
            for (int m=0;m<8;m++) acc[m] += h1[m][k]*w;
        }
        #pragma unroll
        for (int m=0;m<8;m++) h2[m][c] = acc[m]>0.f?acc[m]:0.f;
    }
    __syncthreads();
    {
        int c = tid;
        float acc[8];
        #pragma unroll
        for (int m=0;m<8;m++) acc[m] = bf2[c];
        for (int k=0;k<256;k++){
            float w = Wf2[k*256+c];
            #pragma unroll
            for (int m=0;m<8;m++) acc[m] += h2[m][k]*w;
        }
        #pragma unroll
        for (int m=0;m<8;m++) h3[m][c] = acc[m]>0.f?acc[m]:0.f;
    }
    __syncthreads();
    int w = tid >> 6, lane = tid & 63;
    #pragma unroll
    for (int mm=0; mm<2; ++mm){
        int m = w*2 + mm;
        float4 acc = {0,0,0,0};
        #pragma unroll
        for (int q=0;q<4;q++){
            int k = lane + q*64;
            float hv = h3[m][k];
            float4 w3 = *(const float4*)&Wf3[k*4];
            acc.x += hv*w3.x; acc.y += hv*w3.y; acc.z += hv*w3.z; acc.w += hv*w3.w;
        }
        #pragma unroll
        for (int s=1; s<64; s<<=1){
            acc.x += __shfl_xor(acc.x, s, 64);
            acc.y += __shfl_xor(acc.y, s, 64);
            acc.z += __shfl_xor(acc.z, s, 64);
            acc.w += __shfl_xor(acc.w, s, 64);
        }
        if (lane == 0){
            float4 o;
            o.x = acc.x + bf3[0]; o.y = acc.y + bf3[1];
            o.z = acc.z + bf3[2]; o.w = acc.w + bf3[3];
            *(float4*)&out[(n0+m)*4] = o;
        }
    }
}

// ---------- host ----------
extern "C" void kernel_launch(void* const* d_in, const int* in_sizes, int n_in,
                              void* d_out, int out_size, void* d_ws, size_t ws_size,
                              hipStream_t stream){
    const float* dx1  = (const float*)d_in[0];
    const float* dx2  = (const float*)d_in[1];
    const float* Wk   = (const float*)d_in[2];
    const float* bk   = (const float*)d_in[3];
    const float* Wg1  = (const float*)d_in[4];
    const float* bg1  = (const float*)d_in[5];
    const float* Wg2  = (const float*)d_in[6];
    const float* bg2  = (const float*)d_in[7];
    const float* Wq   = (const float*)d_in[8];
    const float* bq   = (const float*)d_in[9];
    const float* Wkey = (const float*)d_in[10];
    const float* bkey = (const float*)d_in[11];
    const float* Woff = (const float*)d_in[12];
    const float* boff = (const float*)d_in[13];
    const float* pw   = (const float*)d_in[14];
    const float* Wf1  = (const float*)d_in[15];
    const float* bf1  = (const float*)d_in[16];
    const float* Wf2  = (const float*)d_in[17];
    const float* bf2  = (const float*)d_in[18];
    const float* Wf3  = (const float*)d_in[19];
    const float* bf3  = (const float*)d_in[20];
    const float* Wcy3 = (const float*)d_in[21];
    const float* bcy3 = (const float*)d_in[22];
    const float* Wcx3 = (const float*)d_in[23];
    const float* bcx3 = (const float*)d_in[24];
    const float* Wcy5 = (const float*)d_in[25];
    const float* bcy5 = (const float*)d_in[26];
    const float* Wcx5 = (const float*)d_in[27];
    const float* bcx5 = (const float*)d_in[28];
    const float* Wcy9 = (const float*)d_in[29];
    const float* bcy9 = (const float*)d_in[30];
    const float* Wcx9 = (const float*)d_in[31];
    const float* bcx9 = (const float*)d_in[32];

    char* ws = (char*)d_ws;
    size_t off = 0;
    auto alloc = [&](size_t b)->void*{ void* p = ws + off; off += (b + 255) & ~(size_t)255; return p; };

    // --- zero-init region (one small memset) ---
    char* zbase = ws + off;
    float*    colsum    = (float*)   alloc(4*4);
    int*      cnt3      = (int*)     alloc((size_t)NN*4);
    int*      cnt5      = (int*)     alloc((size_t)NN*4);
    int*      cnt9      = (int*)     alloc((size_t)NN*4);
    int*      cur       = (int*)     alloc((size_t)3*NN*4);
    unsigned* rowmaxenc = (unsigned*)alloc((size_t)NN*4);
    size_t zbytes = (size_t)((ws + off) - zbase);
    unsigned* rowminenc = (unsigned*)alloc((size_t)NN*4);   // memset 0xFF

    // --- non-zeroed ---
    float*  x0    = (float*) alloc((size_t)NN*8*4);
    float2* pos   = (float2*)alloc((size_t)NN*8);
    float4* otp   = (float4*)alloc((size_t)NN*16);
    float*  maxd  = (float*) alloc((size_t)NN*4);
    int*    nbr   = (int*)   alloc((size_t)NN*9*4);
    int*    offc  = (int*)   alloc((size_t)3*NN*4);
    float*  dinvc = (float*) alloc((size_t)3*NN*4);
    int*    rev   = (int*)   alloc((size_t)NN*17*4);
    float*  xw    = (float*) alloc((size_t)NN*64*4);
    float*  y2    = (float*) alloc((size_t)3*NN*128*4);
    float*  emb   = (float*) alloc((size_t)NN*384*4);
    __bf16* qh    = (__bf16*)alloc((size_t)NN*128*2);
    __bf16* ql    = (__bf16*)alloc((size_t)NN*128*2);
    __bf16* kh    = (__bf16*)alloc((size_t)NN*128*2);
    __bf16* kl    = (__bf16*)alloc((size_t)NN*128*2);
    float* Tyb    = (float*)alloc((size_t)NN*4*4);
    float* invr   = (float*)alloc((size_t)NN*4);
    float* dOt    = (float*)alloc((size_t)NN*4*4);
    float* kOt    = (float*)alloc((size_t)128*8*4);
    float* ASd    = (float*)alloc((size_t)NN*4*4);
    float* Bv     = (float*)alloc((size_t)NN*4*4);
    float* mnmx   = (float*)alloc((size_t)2*5632*4);
    float* gmm    = (float*)alloc(2*4);
    float* hfin   = (float*)alloc((size_t)NN*4*4);
    (void)ws_size; (void)in_sizes; (void)n_in; (void)out_size;

    hipMemsetAsync(zbase, 0, zbytes, stream);
    hipMemsetAsync(rowminenc, 0xFF, (size_t)NN*4, stream);

    k_prep<<<16,256,0,stream>>>(dx1,dx2,Wk,bk,x0,colsum,pos,otp);
    k_ty  <<<16,256,0,stream>>>(x0,Wcy3,Wcy5,Wcy9,Tyb);
    k_dist<<<NN/4,256,0,stream>>>(pos,otp,maxd,nbr,cnt3,cnt5,cnt9,dOt);
    k_scan<<<1,256,0,stream>>>(cnt3,cnt5,cnt9,offc,dinvc);
    k_fill<<<16,256,0,stream>>>(nbr,offc,cur,rev);

    k_y1  <<<NN*64/256,256,0,stream>>>(x0,Wg1,xw);
    k_h1y2<<<NN/4,256,0,stream>>>(xw,offc,cnt3,cnt5,cnt9,rev,dinvc,bg1,Wg2,y2);
    k_fin <<<NN*3,128,0,stream>>>(y2,offc,cnt3,cnt5,cnt9,rev,dinvc,bg2,emb);

    k_qk<<<NN/8,256,0,stream>>>(emb,Wq,bq,Wkey,bkey,qh,ql,kh,kl);
    k_qkmm<<<2048,256,0,stream>>>(qh,ql,kh,kl,rowmaxenc,rowminenc);
    k_invr<<<16,256,0,stream>>>(rowmaxenc,invr);
    k_kot<<<128,256,0,stream>>>(kh,kl,x0,Tyb,kOt);

    k_convf<<<dim3(74,74),256,0,stream>>>(qh,ql,kh,kl,invr,
        Wcy3,Wcx3,Wcy5,Wcx5,Wcy9,Wcx9,
        bcy3,bcx3,bcy5,bcx5,bcy9,bcx9, mnmx);
    k_asd<<<NN/4,256,0,stream>>>(qh,ql,kOt,invr,maxd,dOt,colsum,
        bcy3,bcx3,bcy5,bcx5,bcy9,bcx9, ASd, Bv);
    k_gmm<<<1,256,0,stream>>>(mnmx,rowminenc,rowmaxenc,gmm);
    k_hfin<<<16,256,0,stream>>>(ASd,Bv,Wcx3,Wcx5,Wcx9,gmm,colsum,hfin);
    k_mlp<<<NN/8,256,0,stream>>>(hfin,Woff,boff,pw,Wf1,bf1,Wf2,bf2,Wf3,bf3,(float*)d_out);
}

// Round 17
// 310.197 us; speedup vs baseline: 1.2894x; 1.2894x over previous
//
#include <hip/hip_runtime.h>
#include <math.h>

#define NN 4096

typedef __bf16 bf16x8 __attribute__((ext_vector_type(8)));
typedef float  f32x4  __attribute__((ext_vector_type(4)));
typedef _Float16 half4 __attribute__((ext_vector_type(4)));

static __device__ __forceinline__ float4 shfl4(float4 v, int src){
    float4 r;
    r.x = __shfl(v.x, src, 64);
    r.y = __shfl(v.y, src, 64);
    r.z = __shfl(v.z, src, 64);
    r.w = __shfl(v.w, src, 64);
    return r;
}
static __device__ __forceinline__ unsigned long long shflx_u64(unsigned long long v, int m){
    unsigned lo = __shfl_xor((unsigned)(v & 0xffffffffu), m, 64);
    unsigned hi = __shfl_xor((unsigned)(v >> 32), m, 64);
    return ((unsigned long long)hi << 32) | lo;
}

// ---------- phase 1: x0 assembly + packed pos/Ot + column sums ----------
__global__ void k_prep(const float* __restrict__ dx1, const float* __restrict__ dx2,
                       const float* __restrict__ Wk, const float* __restrict__ bk,
                       float* __restrict__ x0, float* __restrict__ colsum,
                       float2* __restrict__ pos, float4* __restrict__ otp){
    int n = blockIdx.x*blockDim.x + threadIdx.x;
    if (n >= NN) return;
    float wk[8];
    #pragma unroll
    for (int j=0;j<8;j++) wk[j] = Wk[j];
    float bkv = bk[0];
    float4 d1 = *(const float4*)&dx1[n*4];
    pos[n] = make_float2(d1.x, d1.y);
    #pragma unroll
    for (int c=0;c<4;c++) x0[n*8+c] = (&d1.x)[c];
    float4 ot;
    #pragma unroll
    for (int c=0;c<4;c++){
        float acc = bkv;
        #pragma unroll
        for (int j=0;j<8;j++) acc += dx2[(n*8+j)*4+c]*wk[j];
        x0[n*8+4+c] = acc;
        (&ot.x)[c] = acc;
        atomicAdd(&colsum[c], acc);
    }
    otp[n] = ot;
}

// ---------- phase 1b: Ty[j] = column-conv kernel applied to Ot ----------
__global__ void k_ty(const float* __restrict__ x0,
        const float* __restrict__ Wcy3, const float* __restrict__ Wcy5, const float* __restrict__ Wcy9,
        float* __restrict__ Ty){
    int j = blockIdx.x*256 + threadIdx.x;
    if (j >= NN) return;
    float Cy[9];
    #pragma unroll
    for (int o=-4;o<=4;o++){
        float c = Wcy9[o+4];
        if (o>=-2 && o<=2) c += Wcy5[o+2];
        if (o>=-1 && o<=1) c += Wcy3[o+1];
        Cy[o+4] = c;
    }
    float4 acc = {0,0,0,0};
    #pragma unroll
    for (int o=-4;o<=4;o++){
        int jj = j - o;
        if ((unsigned)jj < NN){
            float4 ot = *(const float4*)&x0[jj*8+4];
            float c = Cy[o+4];
            acc.x += c*ot.x; acc.y += c*ot.y; acc.z += c*ot.z; acc.w += c*ot.w;
        }
    }
    *(float4*)&Ty[j*4] = acc;
}

// ---------- phase 2: two-pass knn: threshold from lane-minima, ballot-compact, extract 9 ----------
#define KCAP 192
__global__ __launch_bounds__(256) void k_dist(const float2* __restrict__ pos,
        const float4* __restrict__ otp,
        float* __restrict__ maxd, int* __restrict__ nbr,
        int* __restrict__ cnt3, int* __restrict__ cnt5, int* __restrict__ cnt9,
        float* __restrict__ dOt){
    __shared__ unsigned long long cbuf[4][KCAP];
    int tid = threadIdx.x;
    int w = tid >> 6, lane = tid & 63;
    int i = blockIdx.x*4 + w;
    float2 pi = pos[i];

    float lmax = 0.f, lmin = INFINITY;
    float4 dacc = {0,0,0,0};
    for (int t=0;t<64;t++){
        int j = (t<<6) | lane;
        float2 p = pos[j];
        float dx = pi.x - p.x, dy = pi.y - p.y;
        float d = sqrtf(dx*dx + dy*dy);
        lmax = fmaxf(lmax, d);
        float4 otj = otp[j];
        dacc.x += d*otj.x; dacc.y += d*otj.y; dacc.z += d*otj.z; dacc.w += d*otj.w;
        if (j != i) lmin = fminf(lmin, d);
    }
    #pragma unroll
    for (int m=1;m<64;m<<=1){
        lmax = fmaxf(lmax, __shfl_xor(lmax, m, 64));
        dacc.x += __shfl_xor(dacc.x, m, 64);
        dacc.y += __shfl_xor(dacc.y, m, 64);
        dacc.z += __shfl_xor(dacc.z, m, 64);
        dacc.w += __shfl_xor(dacc.w, m, 64);
    }
    if (lane==0){
        maxd[i] = lmax;
        *(float4*)&dOt[i*4] = dacc;
    }
    float v = lmin, T = 0.f;
    #pragma unroll
    for (int r=0;r<9;r++){
        float m = v;
        #pragma unroll
        for (int s=1;s<64;s<<=1) m = fminf(m, __shfl_xor(m, s, 64));
        T = m;
        if (v == m) v = INFINITY;
    }

    int base = 0;
    for (int t=0;t<64;t++){
        int j = (t<<6) | lane;
        float2 p = pos[j];
        float dx = pi.x - p.x, dy = pi.y - p.y;
        float d = sqrtf(dx*dx + dy*dy);
        bool pass = (j != i) && (d <= T);
        unsigned long long b = __ballot(pass);
        if (b){
            int pre = __popcll(b & ((1ull<<lane)-1ull));
            int idx = base + pre;
            if (pass && idx < KCAP)
                cbuf[w][idx] = ((unsigned long long)__float_as_uint(d) << 32) | (unsigned)j;
            base += __popcll(b);
        }
    }
    int M = base < KCAP ? base : KCAP;

    unsigned long long c0 = (lane      < M) ? cbuf[w][lane]      : ~0ULL;
    unsigned long long c1 = (lane+64   < M) ? cbuf[w][lane+64]   : ~0ULL;
    unsigned long long c2 = (lane+128  < M) ? cbuf[w][lane+128]  : ~0ULL;
    for (int r=0;r<9;r++){
        unsigned long long mv = c0 < c1 ? c0 : c1;
        mv = mv < c2 ? mv : c2;
        #pragma unroll
        for (int s=1;s<64;s<<=1){
            unsigned long long o = shflx_u64(mv, s);
            if (o < mv) mv = o;
        }
        if (c0 == mv) c0 = ~0ULL;
        else if (c1 == mv) c1 = ~0ULL;
        else if (c2 == mv) c2 = ~0ULL;
        if (lane == 0){
            int j = (int)(mv & 0xffffffffu);
            nbr[i*9+r] = j;
            atomicAdd(&cnt9[j], 1);
            if (r<5) atomicAdd(&cnt5[j], 1);
            if (r<3) atomicAdd(&cnt3[j], 1);
        }
    }
}

// ---------- phase 2b: CSR offsets (exclusive scan) + dinv ----------
__global__ __launch_bounds__(256) void k_scan(const int* __restrict__ cnt3,
        const int* __restrict__ cnt5, const int* __restrict__ cnt9,
        int* __restrict__ offc, float* __restrict__ dinvc){
    __shared__ int part[256];
    int tid = threadIdx.x;
    for (int g=0; g<3; g++){
        const int* cp = g==0?cnt3:(g==1?cnt5:cnt9);
        int base = tid*16;
        int loc[16]; int s=0;
        #pragma unroll
        for (int q=0;q<16;q++){ loc[q]=s; s += cp[base+q]; }
        part[tid]=s; __syncthreads();
        for (int d=1; d<256; d<<=1){
            int v = (tid>=d) ? part[tid-d] : 0;
            __syncthreads();
            part[tid] += v;
            __syncthreads();
        }
        int pre = (tid==0) ? 0 : part[tid-1];
        #pragma unroll
        for (int q=0;q<16;q++){
            offc[g*NN + base + q]  = pre + loc[q];
            dinvc[g*NN + base + q] = rsqrtf((float)cp[base+q] + 1.f);
        }
        __syncthreads();
    }
}

// ---------- phase 2c: fill reverse-edge lists ----------
__global__ void k_fill(const int* __restrict__ nbr, const int* __restrict__ offc,
        int* __restrict__ cur, int* __restrict__ rev){
    int i = blockIdx.x*256 + threadIdx.x;
    if (i >= NN) return;
    #pragma unroll
    for (int t=0;t<9;t++){
        int j = nbr[i*9+t];
        int gmin = t<3 ? 0 : (t<5 ? 1 : 2);
        for (int g=gmin; g<3; g++){
            int pos = atomicAdd(&cur[g*NN+j], 1);
            int rb = (g==0) ? 0 : (g==1 ? NN*3 : NN*8);
            rev[rb + offc[g*NN+j] + pos] = i;
        }
    }
}

// ---------- phase 3: GCN layer-1 input transform ----------
__global__ void k_y1(const float* __restrict__ x0, const float* __restrict__ Wg1,
                     float* __restrict__ xw){
    int idx = blockIdx.x*256 + threadIdx.x;
    if (idx >= NN*64) return;
    int n = idx>>6, c = idx&63;
    float acc = 0.f;
    #pragma unroll
    for (int k=0;k<8;k++) acc += x0[n*8+k]*Wg1[k*64+c];
    xw[idx] = acc;
}

// ---------- phase 3b: gather layer-1 + relu + layer-2 matmul ----------
__global__ __launch_bounds__(256) void k_h1y2(const float* __restrict__ xw,
        const int* __restrict__ offc,
        const int* __restrict__ cnt3, const int* __restrict__ cnt5, const int* __restrict__ cnt9,
        const int* __restrict__ rev, const float* __restrict__ dinvc,
        const float* __restrict__ bg1, const float* __restrict__ Wg2,
        float* __restrict__ y2){
    __shared__ float h1s[12][64];
    int n0 = blockIdx.x*4, tid = threadIdx.x;
    for (int s=tid; s<768; s+=256){
        int p = s>>6, k = s&63, g = p>>2, n = n0+(p&3);
        const int* cp = g==0?cnt3:(g==1?cnt5:cnt9);
        int rb = (g==0) ? 0 : (g==1 ? NN*3 : NN*8);
        int cnt = cp[n];
        int o = rb + offc[g*NN+n];
        float dv = dinvc[g*NN+n];
        float srow = dv*xw[n*64+k];
        for (int e=0;e<cnt;e++){
            int i = rev[o+e];
            srow += dinvc[g*NN+i]*xw[i*64+k];
        }
        float v = dv*srow + bg1[k];
        h1s[p][k] = v>0.f ? v : 0.f;
    }
    __syncthreads();
    int c = tid & 127, ph = tid>>7;
    float a6[6] = {0,0,0,0,0,0};
    for (int k=0;k<64;k++){
        float w = Wg2[k*128+c];
        #pragma unroll
        for (int q=0;q<6;q++) a6[q] += h1s[q*2+ph][k]*w;
    }
    #pragma unroll
    for (int q=0;q<6;q++){
        int p = q*2+ph, g = p>>2, n = n0+(p&3);
        float dv = dinvc[g*NN+n];
        y2[(size_t)g*NN*128 + (size_t)n*128 + c] = dv*a6[q];
    }
}

// ---------- phase 3c: gather layer-2 + bias + log_softmax ----------
__global__ __launch_bounds__(128) void k_fin(const float* __restrict__ y2,
        const int* __restrict__ offc,
        const int* __restrict__ cnt3, const int* __restrict__ cnt5, const int* __restrict__ cnt9,
        const int* __restrict__ rev, const float* __restrict__ dinvc,
        const float* __restrict__ bg2, float* __restrict__ emb){
    __shared__ float sm[2], ss[2];
    int b = blockIdx.x;
    int n = b & (NN-1), g = b >> 12;
    const int* cp = g==0?cnt3:(g==1?cnt5:cnt9);
    int rb = (g==0) ? 0 : (g==1 ? NN*3 : NN*8);
    int cnt = cp[n];
    int o = rb + offc[g*NN+n];
    float dv = dinvc[g*NN+n];
    int c = threadIdx.x;
    const float* yg = y2 + (size_t)g*NN*128;
    float s = yg[(size_t)n*128 + c];
    for (int e=0;e<cnt;e++){
        int i = rev[o+e];
        s += yg[(size_t)i*128 + c];
    }
    float v = dv*s + bg2[c];
    float m = v;
    #pragma unroll
    for (int st=1;st<64;st<<=1) m = fmaxf(m, __shfl_xor(m, st, 64));
    if ((c&63)==0) sm[c>>6] = m;
    __syncthreads();
    m = fmaxf(sm[0], sm[1]);
    float e = expf(v - m);
    float t = e;
    #pragma unroll
    for (int st=1;st<64;st<<=1) t += __shfl_xor(t, st, 64);
    if ((c&63)==0) ss[c>>6] = t;
    __syncthreads();
    t = ss[0]+ss[1];
    emb[n*384 + g*128 + c] = v - m - logf(t);
}

// ---------- phase 4: q/k projections -> bf16 hi/lo split ----------
__global__ __launch_bounds__(256) void k_qk(const float* __restrict__ emb,
        const float* __restrict__ Wq, const float* __restrict__ bq,
        const float* __restrict__ Wkey, const float* __restrict__ bkey,
        __bf16* __restrict__ qh, __bf16* __restrict__ ql,
        __bf16* __restrict__ kh, __bf16* __restrict__ kl){
    __shared__ float es[8][384];
    int n0 = blockIdx.x*8;
    int tid = threadIdx.x;
    for (int idx=tid; idx<8*384; idx+=256){
        int m = idx/384, k = idx%384;
        es[m][k] = emb[(n0+m)*384+k];
    }
    __syncthreads();
    int c = tid & 127;
    int sel = tid >> 7;
    const float* W = sel ? Wkey : Wq;
    float b = sel ? bkey[c] : bq[c];
    float acc[8];
    #pragma unroll
    for (int m=0;m<8;m++) acc[m]=b;
    for (int k=0;k<384;k++){
        float w = W[k*128+c];
        #pragma unroll
        for (int m=0;m<8;m++) acc[m] += es[m][k]*w;
    }
    __bf16* oh = sel ? kh : qh;
    __bf16* ol = sel ? kl : ql;
    #pragma unroll
    for (int m=0;m<8;m++){
        float v = acc[m];
        __bf16 h = (__bf16)v;
        oh[(size_t)(n0+m)*128+c] = h;
        ol[(size_t)(n0+m)*128+c] = (__bf16)(v - (float)h);
    }
}

// ---------- phase 5: scores (fp16) = q @ k^T via bf16-split MFMA ----------
__global__ __launch_bounds__(256) void k_scores(
        const __bf16* __restrict__ qh, const __bf16* __restrict__ ql,
        const __bf16* __restrict__ kh, const __bf16* __restrict__ kl,
        _Float16* __restrict__ scores){
    __shared__ float tl[4][16][36];
    int bx = blockIdx.x & 63;        // col block (64 cols)
    int by = blockIdx.x >> 6;        // row block (128 rows)
    int tid = threadIdx.x;
    int w = tid >> 6, lane = tid & 63;
    int li = lane & 15, g = lane >> 4;
    int r0 = by*128 + (w>>1)*64;
    int c0 = bx*64  + (w&1)*32;

    f32x4 acc[4][2] = {};
    for (int ks=0; ks<4; ++ks){
        int kofs = ks*32 + g*8;
        bf16x8 ah[4], al[4], bh[2], bl[2];
        #pragma unroll
        for (int f=0; f<4; ++f){
            ah[f] = *(const bf16x8*)&qh[(size_t)(r0+f*16+li)*128 + kofs];
            al[f] = *(const bf16x8*)&ql[(size_t)(r0+f*16+li)*128 + kofs];
        }
        #pragma unroll
        for (int f=0; f<2; ++f){
            bh[f] = *(const bf16x8*)&kh[(size_t)(c0+f*16+li)*128 + kofs];
            bl[f] = *(const bf16x8*)&kl[(size_t)(c0+f*16+li)*128 + kofs];
        }
        #pragma unroll
        for (int fr=0; fr<4; ++fr){
            #pragma unroll
            for (int fc=0; fc<2; ++fc){
                acc[fr][fc] = __builtin_amdgcn_mfma_f32_16x16x32_bf16(ah[fr], bh[fc], acc[fr][fc], 0, 0, 0);
                acc[fr][fc] = __builtin_amdgcn_mfma_f32_16x16x32_bf16(ah[fr], bl[fc], acc[fr][fc], 0, 0, 0);
                acc[fr][fc] = __builtin_amdgcn_mfma_f32_16x16x32_bf16(al[fr], bh[fc], acc[fr][fc], 0, 0, 0);
            }
        }
    }
    for (int fr=0; fr<4; ++fr){
        #pragma unroll
        for (int fc=0; fc<2; ++fc)
            #pragma unroll
            for (int r=0; r<4; ++r)
                tl[w][g*4+r][fc*16+li] = acc[fr][fc][r];
        __syncthreads();
        #pragma unroll
        for (int q=0; q<2; ++q){
            int row = q*8 + (lane>>3);
            int c4 = (lane&7)*4;
            float4 v;
            v.x = tl[w][row][c4+0];
            v.y = tl[w][row][c4+1];
            v.z = tl[w][row][c4+2];
            v.w = tl[w][row][c4+3];
            half4 hv = { (_Float16)v.x, (_Float16)v.y, (_Float16)v.z, (_Float16)v.w };
            *(half4*)&scores[(size_t)(r0+fr*16+row)*NN + c0 + c4] = hv;
        }
        __syncthreads();
    }
}

// ---------- phase 5b: per-row max/min/invr from fp16 scores (wave-owned rows) ----------
__global__ __launch_bounds__(256) void k_rowmm(const _Float16* __restrict__ scores,
        float* __restrict__ rowmax, float* __restrict__ rowmin, float* __restrict__ invr){
    int tid = threadIdx.x;
    int w = tid >> 6, lane = tid & 63;
    int i = blockIdx.x*4 + w;
    const _Float16* row = scores + (size_t)i*NN;
    float mx = -INFINITY, mn = INFINITY;
    for (int t=0; t<16; ++t){
        half4 hv = *(const half4*)&row[(t*64+lane)*4];
        float a = (float)hv.x, b = (float)hv.y, c = (float)hv.z, d = (float)hv.w;
        mx = fmaxf(mx, fmaxf(fmaxf(a,b), fmaxf(c,d)));
        mn = fminf(mn, fminf(fminf(a,b), fminf(c,d)));
    }
    #pragma unroll
    for (int s=1; s<64; s<<=1){
        mx = fmaxf(mx, __shfl_xor(mx, s, 64));
        mn = fminf(mn, __shfl_xor(mn, s, 64));
    }
    if (lane == 0){
        rowmax[i] = mx;
        rowmin[i] = mn;
        invr[i] = 1.f/mx;
    }
}

// ---------- phase 6: streaming conv min/max over A (fp16 scores), half4/lane ----------
__global__ __launch_bounds__(256) void k_cconv(const _Float16* __restrict__ scores,
        const float* __restrict__ invr,
        const float* __restrict__ Wcy3, const float* __restrict__ Wcx3,
        const float* __restrict__ Wcy5, const float* __restrict__ Wcx5,
        const float* __restrict__ Wcy9, const float* __restrict__ Wcx9,
        const float* __restrict__ bcy3, const float* __restrict__ bcx3,
        const float* __restrict__ bcy5, const float* __restrict__ bcx5,
        const float* __restrict__ bcy9, const float* __restrict__ bcx9,
        float* __restrict__ mnmx){
    __shared__ float smn[4], smx[4];
    int tid = threadIdx.x;
    int w = tid >> 6, lane = tid & 63;
    int strip = blockIdx.x;                       // 0..16
    int i0 = (blockIdx.y*4 + w)*19;
    int colbase = strip*248 - 4 + lane*4;
    bool lv = (colbase >= 0) && (colbase + 3 < NN);
    bool outLane = (lane >= 1) && (lane < 63) && lv;

    float wy3[3],wx3[3],wy5[5],wx5[5],wy9[9],wx9[9];
    #pragma unroll
    for (int t=0;t<3;t++){ wy3[t]=Wcy3[t]; wx3[t]=Wcx3[t]; }
    #pragma unroll
    for (int t=0;t<5;t++){ wy5[t]=Wcy5[t]; wx5[t]=Wcx5[t]; }
    #pragma unroll
    for (int t=0;t<9;t++){ wy9[t]=Wcy9[t]; wx9[t]=Wcx9[t]; }
    float bc3 = bcy3[0]+bcx3[0];
    float bc5 = bcy5[0]+bcx5[0];
    float bc9 = bcy9[0]+bcx9[0];

    float4 win[9];
    float mn = INFINITY, mx = -INFINITY;
    const int laneL = lane - 1, laneR = lane + 1;

    for (int tb = 0; tb < 3; ++tb){
        #pragma unroll
        for (int u = 0; u < 9; ++u){
            int t  = tb*9 + u;
            int ri = i0 - 4 + t;
            float4 a = make_float4(0,0,0,0);
            if (((unsigned)ri < NN) && lv){
                float iv = invr[ri];
                half4 hv = *(const half4*)&scores[(size_t)ri*NN + colbase];
                a.x = (float)hv.x*iv; a.y = (float)hv.y*iv;
                a.z = (float)hv.z*iv; a.w = (float)hv.w*iv;
            }
            win[u] = a;
            int ro = i0 + t - 8;
            if (t >= 8 && ro < NN){
                float4 ctr = win[(u+5)%9];
                float4 wl = shfl4(ctr, laneL);
                float4 wr = shfl4(ctr, laneR);
                if (outLane){
                    float cw[12] = {wl.x,wl.y,wl.z,wl.w, ctr.x,ctr.y,ctr.z,ctr.w, wr.x,wr.y,wr.z,wr.w};
                    #pragma unroll
                    for (int c=0;c<4;c++){
                        float cx9 = ((win[(u+1)%9][c]*wx9[0] + win[(u+2)%9][c]*wx9[1]) + (win[(u+3)%9][c]*wx9[2] + win[(u+4)%9][c]*wx9[3]))
                                  + ((win[(u+5)%9][c]*wx9[4] + win[(u+6)%9][c]*wx9[5]) + (win[(u+7)%9][c]*wx9[6] + win[(u+8)%9][c]*wx9[7]))
                                  + win[u][c]*wx9[8];
                        float cx5 = ((win[(u+3)%9][c]*wx5[0] + win[(u+4)%9][c]*wx5[1]) + (win[(u+5)%9][c]*wx5[2] + win[(u+6)%9][c]*wx5[3]))
                                  + win[(u+7)%9][c]*wx5[4];
                        float cx3 = (win[(u+4)%9][c]*wx3[0] + win[(u+5)%9][c]*wx3[1]) + win[(u+6)%9][c]*wx3[2];
                        float cy9 = ((cw[c+0]*wy9[0] + cw[c+1]*wy9[1]) + (cw[c+2]*wy9[2] + cw[c+3]*wy9[3]))
                                  + ((cw[c+4]*wy9[4] + cw[c+5]*wy9[5]) + (cw[c+6]*wy9[6] + cw[c+7]*wy9[7]))
                                  + cw[c+8]*wy9[8];
                        float cy5 = ((cw[c+2]*wy5[0] + cw[c+3]*wy5[1]) + (cw[c+4]*wy5[2] + cw[c+5]*wy5[3]))
                                  + cw[c+6]*wy5[4];
                        float cy3 = (cw[c+3]*wy3[0] + cw[c+4]*wy3[1]) + cw[c+5]*wy3[2];
                        float c3v = cy3+cx3+bc3, c5v = cy5+cx5+bc5, c9v = cy9+cx9+bc9;
                        mn = fminf(mn, fminf(fminf(c3v,c5v),c9v));
                        mx = fmaxf(mx, fmaxf(fmaxf(c3v,c5v),c9v));
                    }
                }
            }
        }
    }
    #pragma unroll
    for (int m=1; m<64; m<<=1){
        mn = fminf(mn, __shfl_xor(mn, m, 64));
        mx = fmaxf(mx, __shfl_xor(mx, m, 64));
    }
    if (lane == 0){ smn[w] = mn; smx[w] = mx; }
    __syncthreads();
    if (tid == 0){
        float a0 = fminf(fminf(smn[0],smn[1]), fminf(smn[2],smn[3]));
        float b0 = fmaxf(fmaxf(smx[0],smx[1]), fmaxf(smx[2],smx[3]));
        int bid = blockIdx.y*gridDim.x + blockIdx.x;
        mnmx[bid] = a0;
        mnmx[1024 + bid] = b0;
    }
}

// ---------- phase 6b: kOt[d][0:4]=sum_j k[j][d]*Ot[j], [4:8]=...*Ty[j] ----------
// COALESCED: thread (jj=tid>>7, d=tid&127); wave lanes read 128B contiguous rows;
// ot/ty are wave-broadcast. Register accumulate over 256 rows/block, LDS reduce
// the two row-halves, atomicAdd into zero-initialized kOt (16 blocks x 1024 adds).
__global__ __launch_bounds__(256) void k_kot(const __bf16* __restrict__ kh, const __bf16* __restrict__ kl,
        const float4* __restrict__ otp, const float* __restrict__ Ty,
        float* __restrict__ kOt){
    __shared__ float red[256][8];
    int tid = threadIdx.x;
    int d = tid & 127, jj = tid >> 7;
    float a[8] = {0,0,0,0,0,0,0,0};
    int j0 = blockIdx.x*256;
    for (int it = 0; it < 128; ++it){
        int j = j0 + it*2 + jj;
        float kv = (float)kh[(size_t)j*128 + d] + (float)kl[(size_t)j*128 + d];
        float4 ot = otp[j];
        float4 ty = *(const float4*)&Ty[j*4];
        a[0] += kv*ot.x; a[1] += kv*ot.y; a[2] += kv*ot.z; a[3] += kv*ot.w;
        a[4] += kv*ty.x; a[5] += kv*ty.y; a[6] += kv*ty.z; a[7] += kv*ty.w;
    }
    #pragma unroll
    for (int q=0;q<8;q++) red[tid][q] = a[q];
    __syncthreads();
    if (tid < 128){
        #pragma unroll
        for (int q=0;q<8;q++){
            float s = red[tid][q] + red[tid+128][q];
            atomicAdd(&kOt[tid*8+q], s);
        }
    }
}

// ---------- phase 6c: ASd = invr*(q@kOt), Bv from q@kTy + closed-form ----------
__global__ __launch_bounds__(256) void k_asd(
        const __bf16* __restrict__ qh, const __bf16* __restrict__ ql,
        const float* __restrict__ kOt,
        const float* __restrict__ invr, const float* __restrict__ maxd,
        const float* __restrict__ dOt, const float* __restrict__ colsum,
        const float* __restrict__ bcy3, const float* __restrict__ bcx3,
        const float* __restrict__ bcy5, const float* __restrict__ bcx5,
        const float* __restrict__ bcy9, const float* __restrict__ bcx9,
        float* __restrict__ ASdot, float* __restrict__ Bv){
    __shared__ float kst[128*8];
    int tid = threadIdx.x;
    for (int s = tid; s < 1024; s += 256) kst[s] = kOt[s];
    __syncthreads();
    int lane = tid & 63, r = tid >> 6;
    int i = blockIdx.x*4 + r;
    float a[8] = {0,0,0,0,0,0,0,0};
    #pragma unroll
    for (int dd=0; dd<2; ++dd){
        int d = lane + dd*64;
        float qv = (float)qh[(size_t)i*128 + d] + (float)ql[(size_t)i*128 + d];
        #pragma unroll
        for (int q=0;q<8;q++) a[q] += qv * kst[d*8+q];
    }
    #pragma unroll
    for (int m=1; m<64; m<<=1){
        #pragma unroll
        for (int q=0;q<8;q++) a[q] += __shfl_xor(a[q], m, 64);
    }
    if (lane == 0){
        float iv = invr[i];
        float imv = 1.f/maxd[i];
        float bcsum = bcy3[0]+bcx3[0]+bcy5[0]+bcx5[0]+bcy9[0]+bcx9[0];
        float k = 1.f + bcsum;
        float4 cs = *(const float4*)colsum;
        float4 dv = *(const float4*)&dOt[i*4];
        float4 pa = {iv*a[0], iv*a[1], iv*a[2], iv*a[3]};
        float4 b;
        b.x = cs.x*k - imv*dv.x + iv*a[4];
        b.y = cs.y*k - imv*dv.y + iv*a[5];
        b.z = cs.z*k - imv*dv.z + iv*a[6];
        b.w = cs.w*k - imv*dv.w + iv*a[7];
        *(float4*)&ASdot[i*4] = pa;
        *(float4*)&Bv[i*4]    = b;
    }
}

// ---------- phase 6d: global min/max = conv blocks U A-range U {0,1} ----------
__global__ __launch_bounds__(256) void k_gmm(const float* __restrict__ mnmx,
        const float* __restrict__ rowmin, const float* __restrict__ rowmax,
        float* __restrict__ gmm){
    __shared__ float smn[256], smx[256];
    int tid = threadIdx.x;
    float mn = 0.f, mx = 1.f;   // oushi range is exactly [0,1]
    for (int i=tid; i<NN; i+=256){
        float q = rowmin[i] / rowmax[i];
        mn = fminf(mn, fminf(1.f, q));
        mx = fmaxf(mx, fmaxf(1.f, q));
    }
    for (int b=tid; b<918; b+=256){   // 17 x 54 blocks
        mn = fminf(mn, mnmx[b]);
        mx = fmaxf(mx, mnmx[1024+b]);
    }
    smn[tid]=mn; smx[tid]=mx; __syncthreads();
    for (int s=128;s>0;s>>=1){
        if (tid<s){ smn[tid]=fminf(smn[tid],smn[tid+s]); smx[tid]=fmaxf(smx[tid],smx[tid+s]); }
        __syncthreads();
    }
    if (tid==0){ gmm[0]=smn[0]; gmm[1]=smx[0]; }
}

// ---------- phase 7a: row-conv of ASdot + affine -> hfin ----------
__global__ void k_hfin(const float* __restrict__ ASdot, const float* __restrict__ Bv,
        const float* __restrict__ Wcx3, const float* __restrict__ Wcx5, const float* __restrict__ Wcx9,
        const float* __restrict__ gmm, const float* __restrict__ colsum,
        float* __restrict__ hfin){
    int i = blockIdx.x*256 + threadIdx.x;
    if (i >= NN) return;
    float Cx[9];
    #pragma unroll
    for (int o=-4;o<=4;o++){
        float c = Wcx9[o+4];
        if (o>=-2 && o<=2) c += Wcx5[o+2];
        if (o>=-1 && o<=1) c += Wcx3[o+1];
        Cx[o+4] = c;
    }
    float4 h = *(const float4*)&Bv[i*4];
    float4 a0 = *(const float4*)&ASdot[i*4];
    h.x += a0.x; h.y += a0.y; h.z += a0.z; h.w += a0.w;
    #pragma unroll
    for (int o=-4;o<=4;o++){
        int r = i + o;
        if ((unsigned)r < NN){
            float4 av = *(const float4*)&ASdot[r*4];
            float c = Cx[o+4];
            h.x += c*av.x; h.y += c*av.y; h.z += c*av.z; h.w += c*av.w;
        }
    }
    float mnv = gmm[0], mxv = gmm[1];
    float s = 1.f/(mxv-mnv), oa = -mnv*s;
    float4 cs = *(const float4*)colsum;
    float4 out;
    out.x = s*h.x + 5.f*oa*cs.x;
    out.y = s*h.y + 5.f*oa*cs.y;
    out.z = s*h.z + 5.f*oa*cs.z;
    out.w = s*h.w + 5.f*oa*cs.w;
    *(float4*)&hfin[i*4] = out;
}

// ---------- phase 7b: MLP head (barrier-free epilogue) ----------
__global__ __launch_bounds__(256) void k_mlp(const float* __restrict__ hfin,
        const float* __restrict__ Woff, const float* __restrict__ boff, const float* __restrict__ pw,
        const float* __restrict__ Wf1, const float* __restrict__ bf1,
        const float* __restrict__ Wf2, const float* __restrict__ bf2,
        const float* __restrict__ Wf3, const float* __restrict__ bf3,
        float* __restrict__ out){
    __shared__ float h1[8][128];
    __shared__ float h2[8][256];
    __shared__ float h3[8][256];
    int n0 = blockIdx.x*8, tid = threadIdx.x;
    float p = pw[0];
    {
        int c = tid & 127, mb = (tid>>7)*4;
        #pragma unroll
        for (int mm=0; mm<4; mm++){
            int m = mb+mm;
            float v = boff[c];
            #pragma unroll
            for (int k=0;k<4;k++) v += hfin[(n0+m)*4+k]*Woff[k*128+c];
            h1[m][c] = v>0.f ? v : p*v;
        }
    }
    __syncthreads();
    {
        int c = tid;
        float acc[8];
        #pragma unroll
        for (int m=0;m<8;m++) acc[m] = bf1[c];
        for (int k=0;k<128;k++){
            float w = Wf1[k*256+c];
            #pragma unroll
            for (int m=0;m<8;m++) acc[m] += h1[m][k]*w;
        }
        #pragma unroll
        for (int m=0;m<8;m++) h2[m][c] = acc[m]>0.f?acc[m]:0.f;
    }
    __syncthreads();
    {
        int c = tid;
        float acc[8];
        #pragma unroll
        for (int m=0;m<8;m++) acc[m] = bf2[c];
        for (int k=0;k<256;k++){
            float w = Wf2[k*256+c];
            #pragma unroll
            for (int m=0;m<8;m++) acc[m] += h2[m][k]*w;
        }
        #pragma unroll
        for (int m=0;m<8;m++) h3[m][c] = acc[m]>0.f?acc[m]:0.f;
    }
    __syncthreads();
    int w = tid >> 6, lane = tid & 63;
    #pragma unroll
    for (int mm=0; mm<2; ++mm){
        int m = w*2 + mm;
        float4 acc = {0,0,0,0};
        #pragma unroll
        for (int q=0;q<4;q++){
            int k = lane + q*64;
            float hv = h3[m][k];
            float4 w3 = *(const float4*)&Wf3[k*4];
            acc.x += hv*w3.x; acc.y += hv*w3.y; acc.z += hv*w3.z; acc.w += hv*w3.w;
        }
        #pragma unroll
        for (int s=1; s<64; s<<=1){
            acc.x += __shfl_xor(acc.x, s, 64);
            acc.y += __shfl_xor(acc.y, s, 64);
            acc.z += __shfl_xor(acc.z, s, 64);
            acc.w += __shfl_xor(acc.w, s, 64);
        }
        if (lane == 0){
            float4 o;
            o.x = acc.x + bf3[0]; o.y = acc.y + bf3[1];
            o.z = acc.z + bf3[2]; o.w = acc.w + bf3[3];
            *(float4*)&out[(n0+m)*4] = o;
        }
    }
}

// ---------- host ----------
extern "C" void kernel_launch(void* const* d_in, const int* in_sizes, int n_in,
                              void* d_out, int out_size, void* d_ws, size_t ws_size,
                              hipStream_t stream){
    const float* dx1  = (const float*)d_in[0];
    const float* dx2  = (const float*)d_in[1];
    const float* Wk   = (const float*)d_in[2];
    const float* bk   = (const float*)d_in[3];
    const float* Wg1  = (const float*)d_in[4];
    const float* bg1  = (const float*)d_in[5];
    const float* Wg2  = (const float*)d_in[6];
    const float* bg2  = (const float*)d_in[7];
    const float* Wq   = (const float*)d_in[8];
    const float* bq   = (const float*)d_in[9];
    const float* Wkey = (const float*)d_in[10];
    const float* bkey = (const float*)d_in[11];
    const float* Woff = (const float*)d_in[12];
    const float* boff = (const float*)d_in[13];
    const float* pw   = (const float*)d_in[14];
    const float* Wf1  = (const float*)d_in[15];
    const float* bf1  = (const float*)d_in[16];
    const float* Wf2  = (const float*)d_in[17];
    const float* bf2  = (const float*)d_in[18];
    const float* Wf3  = (const float*)d_in[19];
    const float* bf3  = (const float*)d_in[20];
    const float* Wcy3 = (const float*)d_in[21];
    const float* bcy3 = (const float*)d_in[22];
    const float* Wcx3 = (const float*)d_in[23];
    const float* bcx3 = (const float*)d_in[24];
    const float* Wcy5 = (const float*)d_in[25];
    const float* bcy5 = (const float*)d_in[26];
    const float* Wcx5 = (const float*)d_in[27];
    const float* bcx5 = (const float*)d_in[28];
    const float* Wcy9 = (const float*)d_in[29];
    const float* bcy9 = (const float*)d_in[30];
    const float* Wcx9 = (const float*)d_in[31];
    const float* bcx9 = (const float*)d_in[32];

    char* ws = (char*)d_ws;
    size_t off = 0;
    auto alloc = [&](size_t b)->void*{ void* p = ws + off; off += (b + 255) & ~(size_t)255; return p; };

    // --- zero-init region (one small memset) ---
    char* zbase = ws + off;
    float*    colsum    = (float*)   alloc(4*4);
    int*      cnt3      = (int*)     alloc((size_t)NN*4);
    int*      cnt5      = (int*)     alloc((size_t)NN*4);
    int*      cnt9      = (int*)     alloc((size_t)NN*4);
    int*      cur       = (int*)     alloc((size_t)3*NN*4);
    float*    kOt       = (float*)   alloc((size_t)128*8*4);
    size_t zbytes = (size_t)((ws + off) - zbase);

    // --- non-zeroed ---
    float*  x0    = (float*) alloc((size_t)NN*8*4);
    float2* pos   = (float2*)alloc((size_t)NN*8);
    float4* otp   = (float4*)alloc((size_t)NN*16);
    float*  maxd  = (float*) alloc((size_t)NN*4);
    int*    nbr   = (int*)   alloc((size_t)NN*9*4);
    int*    offc  = (int*)   alloc((size_t)3*NN*4);
    float*  dinvc = (float*) alloc((size_t)3*NN*4);
    int*    rev   = (int*)   alloc((size_t)NN*17*4);
    float*  xw    = (float*) alloc((size_t)NN*64*4);
    float*  y2    = (float*) alloc((size_t)3*NN*128*4);
    float*  emb   = (float*) alloc((size_t)NN*384*4);
    __bf16* qh    = (__bf16*)alloc((size_t)NN*128*2);
    __bf16* ql    = (__bf16*)alloc((size_t)NN*128*2);
    __bf16* kh    = (__bf16*)alloc((size_t)NN*128*2);
    __bf16* kl    = (__bf16*)alloc((size_t)NN*128*2);
    _Float16* scores = (_Float16*)alloc((size_t)NN*NN*2);
    float* Tyb    = (float*)alloc((size_t)NN*4*4);
    float* rowmax = (float*)alloc((size_t)NN*4);
    float* rowmin = (float*)alloc((size_t)NN*4);
    float* invr   = (float*)alloc((size_t)NN*4);
    float* dOt    = (float*)alloc((size_t)NN*4*4);
    float* ASd    = (float*)alloc((size_t)NN*4*4);
    float* Bv     = (float*)alloc((size_t)NN*4*4);
    float* mnmx   = (float*)alloc((size_t)2*1024*4);
    float* gmm    = (float*)alloc(2*4);
    float* hfin   = (float*)alloc((size_t)NN*4*4);
    (void)ws_size; (void)in_sizes; (void)n_in; (void)out_size;

    hipMemsetAsync(zbase, 0, zbytes, stream);

    k_prep<<<16,256,0,stream>>>(dx1,dx2,Wk,bk,x0,colsum,pos,otp);
    k_ty  <<<16,256,0,stream>>>(x0,Wcy3,Wcy5,Wcy9,Tyb);
    k_dist<<<NN/4,256,0,stream>>>(pos,otp,maxd,nbr,cnt3,cnt5,cnt9,dOt);
    k_scan<<<1,256,0,stream>>>(cnt3,cnt5,cnt9,offc,dinvc);
    k_fill<<<16,256,0,stream>>>(nbr,offc,cur,rev);

    k_y1  <<<NN*64/256,256,0,stream>>>(x0,Wg1,xw);
    k_h1y2<<<NN/4,256,0,stream>>>(xw,offc,cnt3,cnt5,cnt9,rev,dinvc,bg1,Wg2,y2);
    k_fin <<<NN*3,128,0,stream>>>(y2,offc,cnt3,cnt5,cnt9,rev,dinvc,bg2,emb);

    k_qk<<<NN/8,256,0,stream>>>(emb,Wq,bq,Wkey,bkey,qh,ql,kh,kl);
    k_scores<<<2048,256,0,stream>>>(qh,ql,kh,kl,scores);
    k_rowmm<<<NN/4,256,0,stream>>>(scores,rowmax,rowmin,invr);
    k_kot<<<16,256,0,stream>>>(kh,kl,otp,Tyb,kOt);

    k_cconv<<<dim3(17,54),256,0,stream>>>(scores,invr,
        Wcy3,Wcx3,Wcy5,Wcx5,Wcy9,Wcx9,
        bcy3,bcx3,bcy5,bcx5,bcy9,bcx9, mnmx);
    k_asd<<<NN/4,256,0,stream>>>(qh,ql,kOt,invr,maxd,dOt,colsum,
        bcy3,bcx3,bcy5,bcx5,bcy9,bcx9, ASd, Bv);
    k_gmm<<<1,256,0,stream>>>(mnmx,rowmin,rowmax,gmm);
    k_hfin<<<16,256,0,stream>>>(ASd,Bv,Wcx3,Wcx5,Wcx9,gmm,colsum,hfin);
    k_mlp<<<NN/8,256,0,stream>>>(hfin,Woff,boff,pw,Wf1,bf1,Wf2,bf2,Wf3,bf3,(float*)d_out);
}

// Round 18
// 289.098 us; speedup vs baseline: 1.3835x; 1.0730x over previous
//
#include <hip/hip_runtime.h>
#include <math.h>

#define NN 4096

typedef _Float16 f16x8 __attribute__((ext_vector_type(8)));
typedef float  f32x4  __attribute__((ext_vector_type(4)));
typedef _Float16 half4 __attribute__((ext_vector_type(4)));

static __device__ __forceinline__ float4 shfl4(float4 v, int src){
    float4 r;
    r.x = __shfl(v.x, src, 64);
    r.y = __shfl(v.y, src, 64);
    r.z = __shfl(v.z, src, 64);
    r.w = __shfl(v.w, src, 64);
    return r;
}
static __device__ __forceinline__ unsigned long long shflx_u64(unsigned long long v, int m){
    unsigned lo = __shfl_xor((unsigned)(v & 0xffffffffu), m, 64);
    unsigned hi = __shfl_xor((unsigned)(v >> 32), m, 64);
    return ((unsigned long long)hi << 32) | lo;
}

// ---------- phase 1: x0 assembly + packed pos/Ot + column sums ----------
__global__ void k_prep(const float* __restrict__ dx1, const float* __restrict__ dx2,
                       const float* __restrict__ Wk, const float* __restrict__ bk,
                       float* __restrict__ x0, float* __restrict__ colsum,
                       float2* __restrict__ pos, float4* __restrict__ otp){
    int n = blockIdx.x*blockDim.x + threadIdx.x;
    if (n >= NN) return;
    float wk[8];
    #pragma unroll
    for (int j=0;j<8;j++) wk[j] = Wk[j];
    float bkv = bk[0];
    float4 d1 = *(const float4*)&dx1[n*4];
    pos[n] = make_float2(d1.x, d1.y);
    #pragma unroll
    for (int c=0;c<4;c++) x0[n*8+c] = (&d1.x)[c];
    float4 ot;
    #pragma unroll
    for (int c=0;c<4;c++){
        float acc = bkv;
        #pragma unroll
        for (int j=0;j<8;j++) acc += dx2[(n*8+j)*4+c]*wk[j];
        x0[n*8+4+c] = acc;
        (&ot.x)[c] = acc;
        atomicAdd(&colsum[c], acc);
    }
    otp[n] = ot;
}

// ---------- phase 1b: Ty[j] = column-conv kernel applied to Ot ----------
__global__ void k_ty(const float* __restrict__ x0,
        const float* __restrict__ Wcy3, const float* __restrict__ Wcy5, const float* __restrict__ Wcy9,
        float* __restrict__ Ty){
    int j = blockIdx.x*256 + threadIdx.x;
    if (j >= NN) return;
    float Cy[9];
    #pragma unroll
    for (int o=-4;o<=4;o++){
        float c = Wcy9[o+4];
        if (o>=-2 && o<=2) c += Wcy5[o+2];
        if (o>=-1 && o<=1) c += Wcy3[o+1];
        Cy[o+4] = c;
    }
    float4 acc = {0,0,0,0};
    #pragma unroll
    for (int o=-4;o<=4;o++){
        int jj = j - o;
        if ((unsigned)jj < NN){
            float4 ot = *(const float4*)&x0[jj*8+4];
            float c = Cy[o+4];
            acc.x += c*ot.x; acc.y += c*ot.y; acc.z += c*ot.z; acc.w += c*ot.w;
        }
    }
    *(float4*)&Ty[j*4] = acc;
}

// ---------- phase 2: two-pass knn: threshold from lane-minima, ballot-compact, extract 9 ----------
#define KCAP 192
__global__ __launch_bounds__(256) void k_dist(const float2* __restrict__ pos,
        const float4* __restrict__ otp,
        float* __restrict__ maxd, int* __restrict__ nbr,
        int* __restrict__ cnt3, int* __restrict__ cnt5, int* __restrict__ cnt9,
        float* __restrict__ dOt){
    __shared__ unsigned long long cbuf[4][KCAP];
    int tid = threadIdx.x;
    int w = tid >> 6, lane = tid & 63;
    int i = blockIdx.x*4 + w;
    float2 pi = pos[i];

    float lmax = 0.f, lmin = INFINITY;
    float4 dacc = {0,0,0,0};
    for (int t=0;t<64;t++){
        int j = (t<<6) | lane;
        float2 p = pos[j];
        float dx = pi.x - p.x, dy = pi.y - p.y;
        float d = sqrtf(dx*dx + dy*dy);
        lmax = fmaxf(lmax, d);
        float4 otj = otp[j];
        dacc.x += d*otj.x; dacc.y += d*otj.y; dacc.z += d*otj.z; dacc.w += d*otj.w;
        if (j != i) lmin = fminf(lmin, d);
    }
    #pragma unroll
    for (int m=1;m<64;m<<=1){
        lmax = fmaxf(lmax, __shfl_xor(lmax, m, 64));
        dacc.x += __shfl_xor(dacc.x, m, 64);
        dacc.y += __shfl_xor(dacc.y, m, 64);
        dacc.z += __shfl_xor(dacc.z, m, 64);
        dacc.w += __shfl_xor(dacc.w, m, 64);
    }
    if (lane==0){
        maxd[i] = lmax;
        *(float4*)&dOt[i*4] = dacc;
    }
    float v = lmin, T = 0.f;
    #pragma unroll
    for (int r=0;r<9;r++){
        float m = v;
        #pragma unroll
        for (int s=1;s<64;s<<=1) m = fminf(m, __shfl_xor(m, s, 64));
        T = m;
        if (v == m) v = INFINITY;
    }

    int base = 0;
    for (int t=0;t<64;t++){
        int j = (t<<6) | lane;
        float2 p = pos[j];
        float dx = pi.x - p.x, dy = pi.y - p.y;
        float d = sqrtf(dx*dx + dy*dy);
        bool pass = (j != i) && (d <= T);
        unsigned long long b = __ballot(pass);
        if (b){
            int pre = __popcll(b & ((1ull<<lane)-1ull));
            int idx = base + pre;
            if (pass && idx < KCAP)
                cbuf[w][idx] = ((unsigned long long)__float_as_uint(d) << 32) | (unsigned)j;
            base += __popcll(b);
        }
    }
    int M = base < KCAP ? base : KCAP;

    unsigned long long c0 = (lane      < M) ? cbuf[w][lane]      : ~0ULL;
    unsigned long long c1 = (lane+64   < M) ? cbuf[w][lane+64]   : ~0ULL;
    unsigned long long c2 = (lane+128  < M) ? cbuf[w][lane+128]  : ~0ULL;
    for (int r=0;r<9;r++){
        unsigned long long mv = c0 < c1 ? c0 : c1;
        mv = mv < c2 ? mv : c2;
        #pragma unroll
        for (int s=1;s<64;s<<=1){
            unsigned long long o = shflx_u64(mv, s);
            if (o < mv) mv = o;
        }
        if (c0 == mv) c0 = ~0ULL;
        else if (c1 == mv) c1 = ~0ULL;
        else if (c2 == mv) c2 = ~0ULL;
        if (lane == 0){
            int j = (int)(mv & 0xffffffffu);
            nbr[i*9+r] = j;
            atomicAdd(&cnt9[j], 1);
            if (r<5) atomicAdd(&cnt5[j], 1);
            if (r<3) atomicAdd(&cnt3[j], 1);
        }
    }
}

// ---------- phase 2b: CSR offsets (exclusive scan) + dinv ----------
__global__ __launch_bounds__(256) void k_scan(const int* __restrict__ cnt3,
        const int* __restrict__ cnt5, const int* __restrict__ cnt9,
        int* __restrict__ offc, float* __restrict__ dinvc){
    __shared__ int part[256];
    int tid = threadIdx.x;
    for (int g=0; g<3; g++){
        const int* cp = g==0?cnt3:(g==1?cnt5:cnt9);
        int base = tid*16;
        int loc[16]; int s=0;
        #pragma unroll
        for (int q=0;q<16;q++){ loc[q]=s; s += cp[base+q]; }
        part[tid]=s; __syncthreads();
        for (int d=1; d<256; d<<=1){
            int v = (tid>=d) ? part[tid-d] : 0;
            __syncthreads();
            part[tid] += v;
            __syncthreads();
        }
        int pre = (tid==0) ? 0 : part[tid-1];
        #pragma unroll
        for (int q=0;q<16;q++){
            offc[g*NN + base + q]  = pre + loc[q];
            dinvc[g*NN + base + q] = rsqrtf((float)cp[base+q] + 1.f);
        }
        __syncthreads();
    }
}

// ---------- phase 2c: fill reverse-edge lists ----------
__global__ void k_fill(const int* __restrict__ nbr, const int* __restrict__ offc,
        int* __restrict__ cur, int* __restrict__ rev){
    int i = blockIdx.x*256 + threadIdx.x;
    if (i >= NN) return;
    #pragma unroll
    for (int t=0;t<9;t++){
        int j = nbr[i*9+t];
        int gmin = t<3 ? 0 : (t<5 ? 1 : 2);
        for (int g=gmin; g<3; g++){
            int pos = atomicAdd(&cur[g*NN+j], 1);
            int rb = (g==0) ? 0 : (g==1 ? NN*3 : NN*8);
            rev[rb + offc[g*NN+j] + pos] = i;
        }
    }
}

// ---------- phase 3: GCN layer-1 input transform ----------
__global__ void k_y1(const float* __restrict__ x0, const float* __restrict__ Wg1,
                     float* __restrict__ xw){
    int idx = blockIdx.x*256 + threadIdx.x;
    if (idx >= NN*64) return;
    int n = idx>>6, c = idx&63;
    float acc = 0.f;
    #pragma unroll
    for (int k=0;k<8;k++) acc += x0[n*8+k]*Wg1[k*64+c];
    xw[idx] = acc;
}

// ---------- phase 3b: gather layer-1 + relu + layer-2 matmul ----------
__global__ __launch_bounds__(256) void k_h1y2(const float* __restrict__ xw,
        const int* __restrict__ offc,
        const int* __restrict__ cnt3, const int* __restrict__ cnt5, const int* __restrict__ cnt9,
        const int* __restrict__ rev, const float* __restrict__ dinvc,
        const float* __restrict__ bg1, const float* __restrict__ Wg2,
        float* __restrict__ y2){
    __shared__ float h1s[12][64];
    int n0 = blockIdx.x*4, tid = threadIdx.x;
    for (int s=tid; s<768; s+=256){
        int p = s>>6, k = s&63, g = p>>2, n = n0+(p&3);
        const int* cp = g==0?cnt3:(g==1?cnt5:cnt9);
        int rb = (g==0) ? 0 : (g==1 ? NN*3 : NN*8);
        int cnt = cp[n];
        int o = rb + offc[g*NN+n];
        float dv = dinvc[g*NN+n];
        float srow = dv*xw[n*64+k];
        for (int e=0;e<cnt;e++){
            int i = rev[o+e];
            srow += dinvc[g*NN+i]*xw[i*64+k];
        }
        float v = dv*srow + bg1[k];
        h1s[p][k] = v>0.f ? v : 0.f;
    }
    __syncthreads();
    int c = tid & 127, ph = tid>>7;
    float a6[6] = {0,0,0,0,0,0};
    for (int k=0;k<64;k++){
        float w = Wg2[k*128+c];
        #pragma unroll
        for (int q=0;q<6;q++) a6[q] += h1s[q*2+ph][k]*w;
    }
    #pragma unroll
    for (int q=0;q<6;q++){
        int p = q*2+ph, g = p>>2, n = n0+(p&3);
        float dv = dinvc[g*NN+n];
        y2[(size_t)g*NN*128 + (size_t)n*128 + c] = dv*a6[q];
    }
}

// ---------- phase 3c: gather layer-2 + bias + log_softmax ----------
__global__ __launch_bounds__(128) void k_fin(const float* __restrict__ y2,
        const int* __restrict__ offc,
        const int* __restrict__ cnt3, const int* __restrict__ cnt5, const int* __restrict__ cnt9,
        const int* __restrict__ rev, const float* __restrict__ dinvc,
        const float* __restrict__ bg2, float* __restrict__ emb){
    __shared__ float sm[2], ss[2];
    int b = blockIdx.x;
    int n = b & (NN-1), g = b >> 12;
    const int* cp = g==0?cnt3:(g==1?cnt5:cnt9);
    int rb = (g==0) ? 0 : (g==1 ? NN*3 : NN*8);
    int cnt = cp[n];
    int o = rb + offc[g*NN+n];
    float dv = dinvc[g*NN+n];
    int c = threadIdx.x;
    const float* yg = y2 + (size_t)g*NN*128;
    float s = yg[(size_t)n*128 + c];
    for (int e=0;e<cnt;e++){
        int i = rev[o+e];
        s += yg[(size_t)i*128 + c];
    }
    float v = dv*s + bg2[c];
    float m = v;
    #pragma unroll
    for (int st=1;st<64;st<<=1) m = fmaxf(m, __shfl_xor(m, st, 64));
    if ((c&63)==0) sm[c>>6] = m;
    __syncthreads();
    m = fmaxf(sm[0], sm[1]);
    float e = expf(v - m);
    float t = e;
    #pragma unroll
    for (int st=1;st<64;st<<=1) t += __shfl_xor(t, st, 64);
    if ((c&63)==0) ss[c>>6] = t;
    __syncthreads();
    t = ss[0]+ss[1];
    emb[n*384 + g*128 + c] = v - m - logf(t);
}

// ---------- phase 4: q/k projections -> fp16 (single copy; split deleted) ----------
__global__ __launch_bounds__(256) void k_qk(const float* __restrict__ emb,
        const float* __restrict__ Wq, const float* __restrict__ bq,
        const float* __restrict__ Wkey, const float* __restrict__ bkey,
        _Float16* __restrict__ qe, _Float16* __restrict__ ke){
    __shared__ float es[8][384];
    int n0 = blockIdx.x*8;
    int tid = threadIdx.x;
    for (int idx=tid; idx<8*384; idx+=256){
        int m = idx/384, k = idx%384;
        es[m][k] = emb[(n0+m)*384+k];
    }
    __syncthreads();
    int c = tid & 127;
    int sel = tid >> 7;
    const float* W = sel ? Wkey : Wq;
    float b = sel ? bkey[c] : bq[c];
    float acc[8];
    #pragma unroll
    for (int m=0;m<8;m++) acc[m]=b;
    for (int k=0;k<384;k++){
        float w = W[k*128+c];
        #pragma unroll
        for (int m=0;m<8;m++) acc[m] += es[m][k]*w;
    }
    _Float16* oe = sel ? ke : qe;
    #pragma unroll
    for (int m=0;m<8;m++)
        oe[(size_t)(n0+m)*128+c] = (_Float16)acc[m];
}

// ---------- phase 5: scores (fp16) = q @ k^T, single-pass fp16 MFMA ----------
// fp16 dot error ~2^-11*sqrt(K) ~ 0.1-0.2% -- only ~2-4x the fp16 storage
// rounding already applied. Loads 6/ks (was 12), MFMA 8/ks (was 24).
__global__ __launch_bounds__(256) void k_scores(
        const _Float16* __restrict__ qe, const _Float16* __restrict__ ke,
        _Float16* __restrict__ scores){
    __shared__ float tl[4][16][36];
    int bx = blockIdx.x & 63;        // col block (64 cols)
    int by = blockIdx.x >> 6;        // row block (128 rows)
    int tid = threadIdx.x;
    int w = tid >> 6, lane = tid & 63;
    int li = lane & 15, g = lane >> 4;
    int r0 = by*128 + (w>>1)*64;
    int c0 = bx*64  + (w&1)*32;

    f32x4 acc[4][2] = {};
    for (int ks=0; ks<4; ++ks){
        int kofs = ks*32 + g*8;
        f16x8 ah[4], bh[2];
        #pragma unroll
        for (int f=0; f<4; ++f)
            ah[f] = *(const f16x8*)&qe[(size_t)(r0+f*16+li)*128 + kofs];
        #pragma unroll
        for (int f=0; f<2; ++f)
            bh[f] = *(const f16x8*)&ke[(size_t)(c0+f*16+li)*128 + kofs];
        #pragma unroll
        for (int fr=0; fr<4; ++fr){
            #pragma unroll
            for (int fc=0; fc<2; ++fc){
                acc[fr][fc] = __builtin_amdgcn_mfma_f32_16x16x32_f16(ah[fr], bh[fc], acc[fr][fc], 0, 0, 0);
            }
        }
    }
    for (int fr=0; fr<4; ++fr){
        #pragma unroll
        for (int fc=0; fc<2; ++fc)
            #pragma unroll
            for (int r=0; r<4; ++r)
                tl[w][g*4+r][fc*16+li] = acc[fr][fc][r];
        __syncthreads();
        #pragma unroll
        for (int q=0; q<2; ++q){
            int row = q*8 + (lane>>3);
            int c4 = (lane&7)*4;
            float4 v;
            v.x = tl[w][row][c4+0];
            v.y = tl[w][row][c4+1];
            v.z = tl[w][row][c4+2];
            v.w = tl[w][row][c4+3];
            half4 hv = { (_Float16)v.x, (_Float16)v.y, (_Float16)v.z, (_Float16)v.w };
            *(half4*)&scores[(size_t)(r0+fr*16+row)*NN + c0 + c4] = hv;
        }
        __syncthreads();
    }
}

// ---------- phase 5b: per-row max/min/invr from fp16 scores (wave-owned rows) ----------
__global__ __launch_bounds__(256) void k_rowmm(const _Float16* __restrict__ scores,
        float* __restrict__ rowmax, float* __restrict__ rowmin, float* __restrict__ invr){
    int tid = threadIdx.x;
    int w = tid >> 6, lane = tid & 63;
    int i = blockIdx.x*4 + w;
    const _Float16* row = scores + (size_t)i*NN;
    float mx = -INFINITY, mn = INFINITY;
    for (int t=0; t<16; ++t){
        half4 hv = *(const half4*)&row[(t*64+lane)*4];
        float a = (float)hv.x, b = (float)hv.y, c = (float)hv.z, d = (float)hv.w;
        mx = fmaxf(mx, fmaxf(fmaxf(a,b), fmaxf(c,d)));
        mn = fminf(mn, fminf(fminf(a,b), fminf(c,d)));
    }
    #pragma unroll
    for (int s=1; s<64; s<<=1){
        mx = fmaxf(mx, __shfl_xor(mx, s, 64));
        mn = fminf(mn, __shfl_xor(mn, s, 64));
    }
    if (lane == 0){
        rowmax[i] = mx;
        rowmin[i] = mn;
        invr[i] = 1.f/mx;
    }
}

// ---------- phase 6: streaming conv min/max over A (fp16 scores), half4/lane ----------
__global__ __launch_bounds__(256) void k_cconv(const _Float16* __restrict__ scores,
        const float* __restrict__ invr,
        const float* __restrict__ Wcy3, const float* __restrict__ Wcx3,
        const float* __restrict__ Wcy5, const float* __restrict__ Wcx5,
        const float* __restrict__ Wcy9, const float* __restrict__ Wcx9,
        const float* __restrict__ bcy3, const float* __restrict__ bcx3,
        const float* __restrict__ bcy5, const float* __restrict__ bcx5,
        const float* __restrict__ bcy9, const float* __restrict__ bcx9,
        float* __restrict__ mnmx){
    __shared__ float smn[4], smx[4];
    int tid = threadIdx.x;
    int w = tid >> 6, lane = tid & 63;
    int strip = blockIdx.x;                       // 0..16
    int i0 = (blockIdx.y*4 + w)*19;
    int colbase = strip*248 - 4 + lane*4;
    bool lv = (colbase >= 0) && (colbase + 3 < NN);
    bool outLane = (lane >= 1) && (lane < 63) && lv;

    float wy3[3],wx3[3],wy5[5],wx5[5],wy9[9],wx9[9];
    #pragma unroll
    for (int t=0;t<3;t++){ wy3[t]=Wcy3[t]; wx3[t]=Wcx3[t]; }
    #pragma unroll
    for (int t=0;t<5;t++){ wy5[t]=Wcy5[t]; wx5[t]=Wcx5[t]; }
    #pragma unroll
    for (int t=0;t<9;t++){ wy9[t]=Wcy9[t]; wx9[t]=Wcx9[t]; }
    float bc3 = bcy3[0]+bcx3[0];
    float bc5 = bcy5[0]+bcx5[0];
    float bc9 = bcy9[0]+bcx9[0];

    float4 win[9];
    float mn = INFINITY, mx = -INFINITY;
    const int laneL = lane - 1, laneR = lane + 1;

    for (int tb = 0; tb < 3; ++tb){
        #pragma unroll
        for (int u = 0; u < 9; ++u){
            int t  = tb*9 + u;
            int ri = i0 - 4 + t;
            float4 a = make_float4(0,0,0,0);
            if (((unsigned)ri < NN) && lv){
                float iv = invr[ri];
                half4 hv = *(const half4*)&scores[(size_t)ri*NN + colbase];
                a.x = (float)hv.x*iv; a.y = (float)hv.y*iv;
                a.z = (float)hv.z*iv; a.w = (float)hv.w*iv;
            }
            win[u] = a;
            int ro = i0 + t - 8;
            if (t >= 8 && ro < NN){
                float4 ctr = win[(u+5)%9];
                float4 wl = shfl4(ctr, laneL);
                float4 wr = shfl4(ctr, laneR);
                if (outLane){
                    float cw[12] = {wl.x,wl.y,wl.z,wl.w, ctr.x,ctr.y,ctr.z,ctr.w, wr.x,wr.y,wr.z,wr.w};
                    #pragma unroll
                    for (int c=0;c<4;c++){
                        float cx9 = ((win[(u+1)%9][c]*wx9[0] + win[(u+2)%9][c]*wx9[1]) + (win[(u+3)%9][c]*wx9[2] + win[(u+4)%9][c]*wx9[3]))
                                  + ((win[(u+5)%9][c]*wx9[4] + win[(u+6)%9][c]*wx9[5]) + (win[(u+7)%9][c]*wx9[6] + win[(u+8)%9][c]*wx9[7]))
                                  + win[u][c]*wx9[8];
                        float cx5 = ((win[(u+3)%9][c]*wx5[0] + win[(u+4)%9][c]*wx5[1]) + (win[(u+5)%9][c]*wx5[2] + win[(u+6)%9][c]*wx5[3]))
                                  + win[(u+7)%9][c]*wx5[4];
                        float cx3 = (win[(u+4)%9][c]*wx3[0] + win[(u+5)%9][c]*wx3[1]) + win[(u+6)%9][c]*wx3[2];
                        float cy9 = ((cw[c+0]*wy9[0] + cw[c+1]*wy9[1]) + (cw[c+2]*wy9[2] + cw[c+3]*wy9[3]))
                                  + ((cw[c+4]*wy9[4] + cw[c+5]*wy9[5]) + (cw[c+6]*wy9[6] + cw[c+7]*wy9[7]))
                                  + cw[c+8]*wy9[8];
                        float cy5 = ((cw[c+2]*wy5[0] + cw[c+3]*wy5[1]) + (cw[c+4]*wy5[2] + cw[c+5]*wy5[3]))
                                  + cw[c+6]*wy5[4];
                        float cy3 = (cw[c+3]*wy3[0] + cw[c+4]*wy3[1]) + cw[c+5]*wy3[2];
                        float c3v = cy3+cx3+bc3, c5v = cy5+cx5+bc5, c9v = cy9+cx9+bc9;
                        mn = fminf(mn, fminf(fminf(c3v,c5v),c9v));
                        mx = fmaxf(mx, fmaxf(fmaxf(c3v,c5v),c9v));
                    }
                }
            }
        }
    }
    #pragma unroll
    for (int m=1; m<64; m<<=1){
        mn = fminf(mn, __shfl_xor(mn, m, 64));
        mx = fmaxf(mx, __shfl_xor(mx, m, 64));
    }
    if (lane == 0){ smn[w] = mn; smx[w] = mx; }
    __syncthreads();
    if (tid == 0){
        float a0 = fminf(fminf(smn[0],smn[1]), fminf(smn[2],smn[3]));
        float b0 = fmaxf(fmaxf(smx[0],smx[1]), fmaxf(smx[2],smx[3]));
        int bid = blockIdx.y*gridDim.x + blockIdx.x;
        mnmx[bid] = a0;
        mnmx[1024 + bid] = b0;
    }
}

// ---------- phase 6b: kOt[d][0:4]=sum_j k[j][d]*Ot[j], [4:8]=...*Ty[j] ----------
__global__ __launch_bounds__(256) void k_kot(const _Float16* __restrict__ ke,
        const float4* __restrict__ otp, const float* __restrict__ Ty,
        float* __restrict__ kOt){
    __shared__ float red[256][8];
    int tid = threadIdx.x;
    int d = tid & 127, jj = tid >> 7;
    float a[8] = {0,0,0,0,0,0,0,0};
    int j0 = blockIdx.x*256;
    for (int it = 0; it < 128; ++it){
        int j = j0 + it*2 + jj;
        float kv = (float)ke[(size_t)j*128 + d];
        float4 ot = otp[j];
        float4 ty = *(const float4*)&Ty[j*4];
        a[0] += kv*ot.x; a[1] += kv*ot.y; a[2] += kv*ot.z; a[3] += kv*ot.w;
        a[4] += kv*ty.x; a[5] += kv*ty.y; a[6] += kv*ty.z; a[7] += kv*ty.w;
    }
    #pragma unroll
    for (int q=0;q<8;q++) red[tid][q] = a[q];
    __syncthreads();
    if (tid < 128){
        #pragma unroll
        for (int q=0;q<8;q++){
            float s = red[tid][q] + red[tid+128][q];
            atomicAdd(&kOt[tid*8+q], s);
        }
    }
}

// ---------- phase 6c: ASd = invr*(q@kOt), Bv from q@kTy + closed-form ----------
__global__ __launch_bounds__(256) void k_asd(
        const _Float16* __restrict__ qe,
        const float* __restrict__ kOt,
        const float* __restrict__ invr, const float* __restrict__ maxd,
        const float* __restrict__ dOt, const float* __restrict__ colsum,
        const float* __restrict__ bcy3, const float* __restrict__ bcx3,
        const float* __restrict__ bcy5, const float* __restrict__ bcx5,
        const float* __restrict__ bcy9, const float* __restrict__ bcx9,
        float* __restrict__ ASdot, float* __restrict__ Bv){
    __shared__ float kst[128*8];
    int tid = threadIdx.x;
    for (int s = tid; s < 1024; s += 256) kst[s] = kOt[s];
    __syncthreads();
    int lane = tid & 63, r = tid >> 6;
    int i = blockIdx.x*4 + r;
    float a[8] = {0,0,0,0,0,0,0,0};
    #pragma unroll
    for (int dd=0; dd<2; ++dd){
        int d = lane + dd*64;
        float qv = (float)qe[(size_t)i*128 + d];
        #pragma unroll
        for (int q=0;q<8;q++) a[q] += qv * kst[d*8+q];
    }
    #pragma unroll
    for (int m=1; m<64; m<<=1){
        #pragma unroll
        for (int q=0;q<8;q++) a[q] += __shfl_xor(a[q], m, 64);
    }
    if (lane == 0){
        float iv = invr[i];
        float imv = 1.f/maxd[i];
        float bcsum = bcy3[0]+bcx3[0]+bcy5[0]+bcx5[0]+bcy9[0]+bcx9[0];
        float k = 1.f + bcsum;
        float4 cs = *(const float4*)colsum;
        float4 dv = *(const float4*)&dOt[i*4];
        float4 pa = {iv*a[0], iv*a[1], iv*a[2], iv*a[3]};
        float4 b;
        b.x = cs.x*k - imv*dv.x + iv*a[4];
        b.y = cs.y*k - imv*dv.y + iv*a[5];
        b.z = cs.z*k - imv*dv.z + iv*a[6];
        b.w = cs.w*k - imv*dv.w + iv*a[7];
        *(float4*)&ASdot[i*4] = pa;
        *(float4*)&Bv[i*4]    = b;
    }
}

// ---------- phase 6d: global min/max = conv blocks U A-range U {0,1} ----------
__global__ __launch_bounds__(256) void k_gmm(const float* __restrict__ mnmx,
        const float* __restrict__ rowmin, const float* __restrict__ rowmax,
        float* __restrict__ gmm){
    __shared__ float smn[256], smx[256];
    int tid = threadIdx.x;
    float mn = 0.f, mx = 1.f;   // oushi range is exactly [0,1]
    for (int i=tid; i<NN; i+=256){
        float q = rowmin[i] / rowmax[i];
        mn = fminf(mn, fminf(1.f, q));
        mx = fmaxf(mx, fmaxf(1.f, q));
    }
    for (int b=tid; b<918; b+=256){   // 17 x 54 blocks
        mn = fminf(mn, mnmx[b]);
        mx = fmaxf(mx, mnmx[1024+b]);
    }
    smn[tid]=mn; smx[tid]=mx; __syncthreads();
    for (int s=128;s>0;s>>=1){
        if (tid<s){ smn[tid]=fminf(smn[tid],smn[tid+s]); smx[tid]=fmaxf(smx[tid],smx[tid+s]); }
        __syncthreads();
    }
    if (tid==0){ gmm[0]=smn[0]; gmm[1]=smx[0]; }
}

// ---------- phase 7a: row-conv of ASdot + affine -> hfin ----------
__global__ void k_hfin(const float* __restrict__ ASdot, const float* __restrict__ Bv,
        const float* __restrict__ Wcx3, const float* __restrict__ Wcx5, const float* __restrict__ Wcx9,
        const float* __restrict__ gmm, const float* __restrict__ colsum,
        float* __restrict__ hfin){
    int i = blockIdx.x*256 + threadIdx.x;
    if (i >= NN) return;
    float Cx[9];
    #pragma unroll
    for (int o=-4;o<=4;o++){
        float c = Wcx9[o+4];
        if (o>=-2 && o<=2) c += Wcx5[o+2];
        if (o>=-1 && o<=1) c += Wcx3[o+1];
        Cx[o+4] = c;
    }
    float4 h = *(const float4*)&Bv[i*4];
    float4 a0 = *(const float4*)&ASdot[i*4];
    h.x += a0.x; h.y += a0.y; h.z += a0.z; h.w += a0.w;
    #pragma unroll
    for (int o=-4;o<=4;o++){
        int r = i + o;
        if ((unsigned)r < NN){
            float4 av = *(const float4*)&ASdot[r*4];
            float c = Cx[o+4];
            h.x += c*av.x; h.y += c*av.y; h.z += c*av.z; h.w += c*av.w;
        }
    }
    float mnv = gmm[0], mxv = gmm[1];
    float s = 1.f/(mxv-mnv), oa = -mnv*s;
    float4 cs = *(const float4*)colsum;
    float4 out;
    out.x = s*h.x + 5.f*oa*cs.x;
    out.y = s*h.y + 5.f*oa*cs.y;
    out.z = s*h.z + 5.f*oa*cs.z;
    out.w = s*h.w + 5.f*oa*cs.w;
    *(float4*)&hfin[i*4] = out;
}

// ---------- phase 7b: MLP head (barrier-free epilogue) ----------
__global__ __launch_bounds__(256) void k_mlp(const float* __restrict__ hfin,
        const float* __restrict__ Woff, const float* __restrict__ boff, const float* __restrict__ pw,
        const float* __restrict__ Wf1, const float* __restrict__ bf1,
        const float* __restrict__ Wf2, const float* __restrict__ bf2,
        const float* __restrict__ Wf3, const float* __restrict__ bf3,
        float* __restrict__ out){
    __shared__ float h1[8][128];
    __shared__ float h2[8][256];
    __shared__ float h3[8][256];
    int n0 = blockIdx.x*8, tid = threadIdx.x;
    float p = pw[0];
    {
        int c = tid & 127, mb = (tid>>7)*4;
        #pragma unroll
        for (int mm=0; mm<4; mm++){
            int m = mb+mm;
            float v = boff[c];
            #pragma unroll
            for (int k=0;k<4;k++) v += hfin[(n0+m)*4+k]*Woff[k*128+c];
            h1[m][c] = v>0.f ? v : p*v;
        }
    }
    __syncthreads();
    {
        int c = tid;
        float acc[8];
        #pragma unroll
        for (int m=0;m<8;m++) acc[m] = bf1[c];
        for (int k=0;k<128;k++){
            float w = Wf1[k*256+c];
            #pragma unroll
            for (int m=0;m<8;m++) acc[m] += h1[m][k]*w;
        }
        #pragma unroll
        for (int m=0;m<8;m++) h2[m][c] = acc[m]>0.f?acc[m]:0.f;
    }
    __syncthreads();
    {
        int c = tid;
        float acc[8];
        #pragma unroll
        for (int m=0;m<8;m++) acc[m] = bf2[c];
        for (int k=0;k<256;k++){
            float w = Wf2[k*256+c];
            #pragma unroll
            for (int m=0;m<8;m++) acc[m] += h2[m][k]*w;
        }
        #pragma unroll
        for (int m=0;m<8;m++) h3[m][c] = acc[m]>0.f?acc[m]:0.f;
    }
    __syncthreads();
    int w = tid >> 6, lane = tid & 63;
    #pragma unroll
    for (int mm=0; mm<2; ++mm){
        int m = w*2 + mm;
        float4 acc = {0,0,0,0};
        #pragma unroll
        for (int q=0;q<4;q++){
            int k = lane + q*64;
            float hv = h3[m][k];
            float4 w3 = *(const float4*)&Wf3[k*4];
            acc.x += hv*w3.x; acc.y += hv*w3.y; acc.z += hv*w3.z; acc.w += hv*w3.w;
        }
        #pragma unroll
        for (int s=1; s<64; s<<=1){
            acc.x += __shfl_xor(acc.x, s, 64);
            acc.y += __shfl_xor(acc.y, s, 64);
            acc.z += __shfl_xor(acc.z, s, 64);
            acc.w += __shfl_xor(acc.w, s, 64);
        }
        if (lane == 0){
            float4 o;
            o.x = acc.x + bf3[0]; o.y = acc.y + bf3[1];
            o.z = acc.z + bf3[2]; o.w = acc.w + bf3[3];
            *(float4*)&out[(n0+m)*4] = o;
        }
    }
}

// ---------- host ----------
extern "C" void kernel_launch(void* const* d_in, const int* in_sizes, int n_in,
                              void* d_out, int out_size, void* d_ws, size_t ws_size,
                              hipStream_t stream){
    const float* dx1  = (const float*)d_in[0];
    const float* dx2  = (const float*)d_in[1];
    const float* Wk   = (const float*)d_in[2];
    const float* bk   = (const float*)d_in[3];
    const float* Wg1  = (const float*)d_in[4];
    const float* bg1  = (const float*)d_in[5];
    const float* Wg2  = (const float*)d_in[6];
    const float* bg2  = (const float*)d_in[7];
    const float* Wq   = (const float*)d_in[8];
    const float* bq   = (const float*)d_in[9];
    const float* Wkey = (const float*)d_in[10];
    const float* bkey = (const float*)d_in[11];
    const float* Woff = (const float*)d_in[12];
    const float* boff = (const float*)d_in[13];
    const float* pw   = (const float*)d_in[14];
    const float* Wf1  = (const float*)d_in[15];
    const float* bf1  = (const float*)d_in[16];
    const float* Wf2  = (const float*)d_in[17];
    const float* bf2  = (const float*)d_in[18];
    const float* Wf3  = (const float*)d_in[19];
    const float* bf3  = (const float*)d_in[20];
    const float* Wcy3 = (const float*)d_in[21];
    const float* bcy3 = (const float*)d_in[22];
    const float* Wcx3 = (const float*)d_in[23];
    const float* bcx3 = (const float*)d_in[24];
    const float* Wcy5 = (const float*)d_in[25];
    const float* bcy5 = (const float*)d_in[26];
    const float* Wcx5 = (const float*)d_in[27];
    const float* bcx5 = (const float*)d_in[28];
    const float* Wcy9 = (const float*)d_in[29];
    const float* bcy9 = (const float*)d_in[30];
    const float* Wcx9 = (const float*)d_in[31];
    const float* bcx9 = (const float*)d_in[32];

    char* ws = (char*)d_ws;
    size_t off = 0;
    auto alloc = [&](size_t b)->void*{ void* p = ws + off; off += (b + 255) & ~(size_t)255; return p; };

    // --- zero-init region (one small memset) ---
    char* zbase = ws + off;
    float*    colsum    = (float*)   alloc(4*4);
    int*      cnt3      = (int*)     alloc((size_t)NN*4);
    int*      cnt5      = (int*)     alloc((size_t)NN*4);
    int*      cnt9      = (int*)     alloc((size_t)NN*4);
    int*      cur       = (int*)     alloc((size_t)3*NN*4);
    float*    kOt       = (float*)   alloc((size_t)128*8*4);
    size_t zbytes = (size_t)((ws + off) - zbase);

    // --- non-zeroed ---
    float*  x0    = (float*) alloc((size_t)NN*8*4);
    float2* pos   = (float2*)alloc((size_t)NN*8);
    float4* otp   = (float4*)alloc((size_t)NN*16);
    float*  maxd  = (float*) alloc((size_t)NN*4);
    int*    nbr   = (int*)   alloc((size_t)NN*9*4);
    int*    offc  = (int*)   alloc((size_t)3*NN*4);
    float*  dinvc = (float*) alloc((size_t)3*NN*4);
    int*    rev   = (int*)   alloc((size_t)NN*17*4);
    float*  xw    = (float*) alloc((size_t)NN*64*4);
    float*  y2    = (float*) alloc((size_t)3*NN*128*4);
    float*  emb   = (float*) alloc((size_t)NN*384*4);
    _Float16* qe  = (_Float16*)alloc((size_t)NN*128*2);
    _Float16* ke  = (_Float16*)alloc((size_t)NN*128*2);
    _Float16* scores = (_Float16*)alloc((size_t)NN*NN*2);
    float* Tyb    = (float*)alloc((size_t)NN*4*4);
    float* rowmax = (float*)alloc((size_t)NN*4);
    float* rowmin = (float*)alloc((size_t)NN*4);
    float* invr   = (float*)alloc((size_t)NN*4);
    float* dOt    = (float*)alloc((size_t)NN*4*4);
    float* ASd    = (float*)alloc((size_t)NN*4*4);
    float* Bv     = (float*)alloc((size_t)NN*4*4);
    float* mnmx   = (float*)alloc((size_t)2*1024*4);
    float* gmm    = (float*)alloc(2*4);
    float* hfin   = (float*)alloc((size_t)NN*4*4);
    (void)ws_size; (void)in_sizes; (void)n_in; (void)out_size;

    hipMemsetAsync(zbase, 0, zbytes, stream);

    k_prep<<<16,256,0,stream>>>(dx1,dx2,Wk,bk,x0,colsum,pos,otp);
    k_ty  <<<16,256,0,stream>>>(x0,Wcy3,Wcy5,Wcy9,Tyb);
    k_dist<<<NN/4,256,0,stream>>>(pos,otp,maxd,nbr,cnt3,cnt5,cnt9,dOt);
    k_scan<<<1,256,0,stream>>>(cnt3,cnt5,cnt9,offc,dinvc);
    k_fill<<<16,256,0,stream>>>(nbr,offc,cur,rev);

    k_y1  <<<NN*64/256,256,0,stream>>>(x0,Wg1,xw);
    k_h1y2<<<NN/4,256,0,stream>>>(xw,offc,cnt3,cnt5,cnt9,rev,dinvc,bg1,Wg2,y2);
    k_fin <<<NN*3,128,0,stream>>>(y2,offc,cnt3,cnt5,cnt9,rev,dinvc,bg2,emb);

    k_qk<<<NN/8,256,0,stream>>>(emb,Wq,bq,Wkey,bkey,qe,ke);
    k_scores<<<2048,256,0,stream>>>(qe,ke,scores);
    k_rowmm<<<NN/4,256,0,stream>>>(scores,rowmax,rowmin,invr);
    k_kot<<<16,256,0,stream>>>(ke,otp,Tyb,kOt);

    k_cconv<<<dim3(17,54),256,0,stream>>>(scores,invr,
        Wcy3,Wcx3,Wcy5,Wcx5,Wcy9,Wcx9,
        bcy3,bcx3,bcy5,bcx5,bcy9,bcx9, mnmx);
    k_asd<<<NN/4,256,0,stream>>>(qe,kOt,invr,maxd,dOt,colsum,
        bcy3,bcx3,bcy5,bcx5,bcy9,bcx9, ASd, Bv);
    k_gmm<<<1,256,0,stream>>>(mnmx,rowmin,rowmax,gmm);
    k_hfin<<<16,256,0,stream>>>(ASd,Bv,Wcx3,Wcx5,Wcx9,gmm,colsum,hfin);
    k_mlp<<<NN/8,256,0,stream>>>(hfin,Woff,boff,pw,Wf1,bf1,Wf2,bf2,Wf3,bf3,(float*)d_out);
}

// Round 19
// 288.306 us; speedup vs baseline: 1.3873x; 1.0027x over previous
//
#include <hip/hip_runtime.h>
#include <math.h>

#define NN 4096

typedef _Float16 f16x8 __attribute__((ext_vector_type(8)));
typedef float  f32x4  __attribute__((ext_vector_type(4)));
typedef _Float16 half4 __attribute__((ext_vector_type(4)));

static __device__ __forceinline__ float4 shfl4(float4 v, int src){
    float4 r;
    r.x = __shfl(v.x, src, 64);
    r.y = __shfl(v.y, src, 64);
    r.z = __shfl(v.z, src, 64);
    r.w = __shfl(v.w, src, 64);
    return r;
}
static __device__ __forceinline__ unsigned long long shflx_u64(unsigned long long v, int m){
    unsigned lo = __shfl_xor((unsigned)(v & 0xffffffffu), m, 64);
    unsigned hi = __shfl_xor((unsigned)(v >> 32), m, 64);
    return ((unsigned long long)hi << 32) | lo;
}

// ---------- phase 1: x0 assembly + packed pos/Ot + column sums ----------
__global__ void k_prep(const float* __restrict__ dx1, const float* __restrict__ dx2,
                       const float* __restrict__ Wk, const float* __restrict__ bk,
                       float* __restrict__ x0, float* __restrict__ colsum,
                       float2* __restrict__ pos, float4* __restrict__ otp){
    int n = blockIdx.x*blockDim.x + threadIdx.x;
    if (n >= NN) return;
    float wk[8];
    #pragma unroll
    for (int j=0;j<8;j++) wk[j] = Wk[j];
    float bkv = bk[0];
    float4 d1 = *(const float4*)&dx1[n*4];
    pos[n] = make_float2(d1.x, d1.y);
    #pragma unroll
    for (int c=0;c<4;c++) x0[n*8+c] = (&d1.x)[c];
    float4 ot;
    #pragma unroll
    for (int c=0;c<4;c++){
        float acc = bkv;
        #pragma unroll
        for (int j=0;j<8;j++) acc += dx2[(n*8+j)*4+c]*wk[j];
        x0[n*8+4+c] = acc;
        (&ot.x)[c] = acc;
        atomicAdd(&colsum[c], acc);
    }
    otp[n] = ot;
}

// ---------- phase 1b: Ty[j] = column-conv kernel applied to Ot ----------
__global__ void k_ty(const float* __restrict__ x0,
        const float* __restrict__ Wcy3, const float* __restrict__ Wcy5, const float* __restrict__ Wcy9,
        float* __restrict__ Ty){
    int j = blockIdx.x*256 + threadIdx.x;
    if (j >= NN) return;
    float Cy[9];
    #pragma unroll
    for (int o=-4;o<=4;o++){
        float c = Wcy9[o+4];
        if (o>=-2 && o<=2) c += Wcy5[o+2];
        if (o>=-1 && o<=1) c += Wcy3[o+1];
        Cy[o+4] = c;
    }
    float4 acc = {0,0,0,0};
    #pragma unroll
    for (int o=-4;o<=4;o++){
        int jj = j - o;
        if ((unsigned)jj < NN){
            float4 ot = *(const float4*)&x0[jj*8+4];
            float c = Cy[o+4];
            acc.x += c*ot.x; acc.y += c*ot.y; acc.z += c*ot.z; acc.w += c*ot.w;
        }
    }
    *(float4*)&Ty[j*4] = acc;
}

// ---------- phase 2: two-pass knn, 2 waves per row (TLP x2), dsq filter in pass 2 ----------
#define KCAP 192
__global__ __launch_bounds__(256) void k_dist(const float2* __restrict__ pos,
        const float4* __restrict__ otp,
        float* __restrict__ maxd, int* __restrict__ nbr,
        int* __restrict__ cnt3, int* __restrict__ cnt5, int* __restrict__ cnt9,
        float* __restrict__ dOt){
    __shared__ unsigned long long cbuf[2][KCAP];
    __shared__ float lmins[2][128];
    __shared__ float pmax[2][2];
    __shared__ float4 pdac[2][2];
    __shared__ int ccnt[2];
    int tid = threadIdx.x;
    int w = tid >> 6, lane = tid & 63;
    int r = w >> 1;                 // row-in-block: 0..1
    int h = w & 1;                  // half-range:  0..1
    int i = blockIdx.x*2 + r;
    float2 pi = pos[i];
    if (tid < 2) ccnt[tid] = 0;

    // pass 1: this wave scans cols [h*2048, h*2048+2048)
    int jbase = h*2048;
    float lmax = 0.f, lmin = INFINITY;
    float4 dacc = {0,0,0,0};
    for (int t=0;t<32;t++){
        int j = jbase + (t<<6) + lane;
        float2 p = pos[j];
        float dx = pi.x - p.x, dy = pi.y - p.y;
        float d = sqrtf(dx*dx + dy*dy);
        lmax = fmaxf(lmax, d);
        float4 otj = otp[j];
        dacc.x += d*otj.x; dacc.y += d*otj.y; dacc.z += d*otj.z; dacc.w += d*otj.w;
        if (j != i) lmin = fminf(lmin, d);
    }
    #pragma unroll
    for (int m=1;m<64;m<<=1){
        lmax = fmaxf(lmax, __shfl_xor(lmax, m, 64));
        dacc.x += __shfl_xor(dacc.x, m, 64);
        dacc.y += __shfl_xor(dacc.y, m, 64);
        dacc.z += __shfl_xor(dacc.z, m, 64);
        dacc.w += __shfl_xor(dacc.w, m, 64);
    }
    if (lane == 0){ pmax[r][h] = lmax; pdac[r][h] = dacc; }
    lmins[r][h*64 + lane] = lmin;
    __syncthreads();
    if (h == 0 && lane == 0){
        maxd[i] = fmaxf(pmax[r][0], pmax[r][1]);
        float4 a = pdac[r][0], b = pdac[r][1];
        float4 s = {a.x+b.x, a.y+b.y, a.z+b.z, a.w+b.w};
        *(float4*)&dOt[i*4] = s;
    }

    // T = 9th extracted min of the 128 lane-minima (both waves compute redundantly)
    float v0 = lmins[r][lane], v1 = lmins[r][64+lane];
    float T = 0.f;
    #pragma unroll
    for (int rr=0; rr<9; rr++){
        float m = fminf(v0, v1);
        #pragma unroll
        for (int s=1;s<64;s<<=1) m = fminf(m, __shfl_xor(m, s, 64));
        T = m;
        if (v0 == m) v0 = INFINITY;
        else if (v1 == m) v1 = INFINITY;
    }
    float Tsq = T*T*1.00001f + 1e-30f;

    // pass 2: conservative dsq filter (superset), compact into shared buffer
    for (int t=0;t<32;t++){
        int j = jbase + (t<<6) + lane;
        float2 p = pos[j];
        float dx = pi.x - p.x, dy = pi.y - p.y;
        float dsq = dx*dx + dy*dy;
        bool pass = (j != i) && (dsq <= Tsq);
        unsigned long long b = __ballot(pass);
        if (b){
            int cntb = __popcll(b);
            int base = 0;
            if (lane == 0) base = atomicAdd(&ccnt[r], cntb);
            base = __shfl(base, 0, 64);
            if (pass){
                float d = sqrtf(dsq);
                int idx = base + __popcll(b & ((1ull<<lane)-1ull));
                if (idx < KCAP)
                    cbuf[r][idx] = ((unsigned long long)__float_as_uint(d) << 32) | (unsigned)j;
            }
        }
    }
    __syncthreads();

    // extraction: wave h==0 of each row picks exact top-9 by (d,j) key
    if (h == 0){
        int M = ccnt[r] < KCAP ? ccnt[r] : KCAP;
        unsigned long long c0 = (lane      < M) ? cbuf[r][lane]      : ~0ULL;
        unsigned long long c1 = (lane+64   < M) ? cbuf[r][lane+64]   : ~0ULL;
        unsigned long long c2 = (lane+128  < M) ? cbuf[r][lane+128]  : ~0ULL;
        for (int rr=0; rr<9; rr++){
            unsigned long long mv = c0 < c1 ? c0 : c1;
            mv = mv < c2 ? mv : c2;
            #pragma unroll
            for (int s=1;s<64;s<<=1){
                unsigned long long o = shflx_u64(mv, s);
                if (o < mv) mv = o;
            }
            if (c0 == mv) c0 = ~0ULL;
            else if (c1 == mv) c1 = ~0ULL;
            else if (c2 == mv) c2 = ~0ULL;
            if (lane == 0){
                int j = (int)(mv & 0xffffffffu);
                nbr[i*9+rr] = j;
                atomicAdd(&cnt9[j], 1);
                if (rr<5) atomicAdd(&cnt5[j], 1);
                if (rr<3) atomicAdd(&cnt3[j], 1);
            }
        }
    }
}

// ---------- phase 2b: CSR offsets (exclusive scan) + dinv ----------
__global__ __launch_bounds__(256) void k_scan(const int* __restrict__ cnt3,
        const int* __restrict__ cnt5, const int* __restrict__ cnt9,
        int* __restrict__ offc, float* __restrict__ dinvc){
    __shared__ int part[256];
    int tid = threadIdx.x;
    for (int g=0; g<3; g++){
        const int* cp = g==0?cnt3:(g==1?cnt5:cnt9);
        int base = tid*16;
        int loc[16]; int s=0;
        #pragma unroll
        for (int q=0;q<16;q++){ loc[q]=s; s += cp[base+q]; }
        part[tid]=s; __syncthreads();
        for (int d=1; d<256; d<<=1){
            int v = (tid>=d) ? part[tid-d] : 0;
            __syncthreads();
            part[tid] += v;
            __syncthreads();
        }
        int pre = (tid==0) ? 0 : part[tid-1];
        #pragma unroll
        for (int q=0;q<16;q++){
            offc[g*NN + base + q]  = pre + loc[q];
            dinvc[g*NN + base + q] = rsqrtf((float)cp[base+q] + 1.f);
        }
        __syncthreads();
    }
}

// ---------- phase 2c: fill reverse-edge lists ----------
__global__ void k_fill(const int* __restrict__ nbr, const int* __restrict__ offc,
        int* __restrict__ cur, int* __restrict__ rev){
    int i = blockIdx.x*256 + threadIdx.x;
    if (i >= NN) return;
    #pragma unroll
    for (int t=0;t<9;t++){
        int j = nbr[i*9+t];
        int gmin = t<3 ? 0 : (t<5 ? 1 : 2);
        for (int g=gmin; g<3; g++){
            int pos = atomicAdd(&cur[g*NN+j], 1);
            int rb = (g==0) ? 0 : (g==1 ? NN*3 : NN*8);
            rev[rb + offc[g*NN+j] + pos] = i;
        }
    }
}

// ---------- phase 3: GCN layer-1 input transform ----------
__global__ void k_y1(const float* __restrict__ x0, const float* __restrict__ Wg1,
                     float* __restrict__ xw){
    int idx = blockIdx.x*256 + threadIdx.x;
    if (idx >= NN*64) return;
    int n = idx>>6, c = idx&63;
    float acc = 0.f;
    #pragma unroll
    for (int k=0;k<8;k++) acc += x0[n*8+k]*Wg1[k*64+c];
    xw[idx] = acc;
}

// ---------- phase 3b: gather layer-1 + relu + layer-2 matmul ----------
__global__ __launch_bounds__(256) void k_h1y2(const float* __restrict__ xw,
        const int* __restrict__ offc,
        const int* __restrict__ cnt3, const int* __restrict__ cnt5, const int* __restrict__ cnt9,
        const int* __restrict__ rev, const float* __restrict__ dinvc,
        const float* __restrict__ bg1, const float* __restrict__ Wg2,
        float* __restrict__ y2){
    __shared__ float h1s[12][64];
    int n0 = blockIdx.x*4, tid = threadIdx.x;
    for (int s=tid; s<768; s+=256){
        int p = s>>6, k = s&63, g = p>>2, n = n0+(p&3);
        const int* cp = g==0?cnt3:(g==1?cnt5:cnt9);
        int rb = (g==0) ? 0 : (g==1 ? NN*3 : NN*8);
        int cnt = cp[n];
        int o = rb + offc[g*NN+n];
        float dv = dinvc[g*NN+n];
        float srow = dv*xw[n*64+k];
        for (int e=0;e<cnt;e++){
            int i = rev[o+e];
            srow += dinvc[g*NN+i]*xw[i*64+k];
        }
        float v = dv*srow + bg1[k];
        h1s[p][k] = v>0.f ? v : 0.f;
    }
    __syncthreads();
    int c = tid & 127, ph = tid>>7;
    float a6[6] = {0,0,0,0,0,0};
    for (int k=0;k<64;k++){
        float w = Wg2[k*128+c];
        #pragma unroll
        for (int q=0;q<6;q++) a6[q] += h1s[q*2+ph][k]*w;
    }
    #pragma unroll
    for (int q=0;q<6;q++){
        int p = q*2+ph, g = p>>2, n = n0+(p&3);
        float dv = dinvc[g*NN+n];
        y2[(size_t)g*NN*128 + (size_t)n*128 + c] = dv*a6[q];
    }
}

// ---------- phase 3c: gather layer-2 + bias + log_softmax ----------
__global__ __launch_bounds__(128) void k_fin(const float* __restrict__ y2,
        const int* __restrict__ offc,
        const int* __restrict__ cnt3, const int* __restrict__ cnt5, const int* __restrict__ cnt9,
        const int* __restrict__ rev, const float* __restrict__ dinvc,
        const float* __restrict__ bg2, float* __restrict__ emb){
    __shared__ float sm[2], ss[2];
    int b = blockIdx.x;
    int n = b & (NN-1), g = b >> 12;
    const int* cp = g==0?cnt3:(g==1?cnt5:cnt9);
    int rb = (g==0) ? 0 : (g==1 ? NN*3 : NN*8);
    int cnt = cp[n];
    int o = rb + offc[g*NN+n];
    float dv = dinvc[g*NN+n];
    int c = threadIdx.x;
    const float* yg = y2 + (size_t)g*NN*128;
    float s = yg[(size_t)n*128 + c];
    for (int e=0;e<cnt;e++){
        int i = rev[o+e];
        s += yg[(size_t)i*128 + c];
    }
    float v = dv*s + bg2[c];
    float m = v;
    #pragma unroll
    for (int st=1;st<64;st<<=1) m = fmaxf(m, __shfl_xor(m, st, 64));
    if ((c&63)==0) sm[c>>6] = m;
    __syncthreads();
    m = fmaxf(sm[0], sm[1]);
    float e = expf(v - m);
    float t = e;
    #pragma unroll
    for (int st=1;st<64;st<<=1) t += __shfl_xor(t, st, 64);
    if ((c&63)==0) ss[c>>6] = t;
    __syncthreads();
    t = ss[0]+ss[1];
    emb[n*384 + g*128 + c] = v - m - logf(t);
}

// ---------- phase 4: q/k projections -> fp16 ----------
__global__ __launch_bounds__(256) void k_qk(const float* __restrict__ emb,
        const float* __restrict__ Wq, const float* __restrict__ bq,
        const float* __restrict__ Wkey, const float* __restrict__ bkey,
        _Float16* __restrict__ qe, _Float16* __restrict__ ke){
    __shared__ float es[8][384];
    int n0 = blockIdx.x*8;
    int tid = threadIdx.x;
    for (int idx=tid; idx<8*384; idx+=256){
        int m = idx/384, k = idx%384;
        es[m][k] = emb[(n0+m)*384+k];
    }
    __syncthreads();
    int c = tid & 127;
    int sel = tid >> 7;
    const float* W = sel ? Wkey : Wq;
    float b = sel ? bkey[c] : bq[c];
    float acc[8];
    #pragma unroll
    for (int m=0;m<8;m++) acc[m]=b;
    for (int k=0;k<384;k++){
        float w = W[k*128+c];
        #pragma unroll
        for (int m=0;m<8;m++) acc[m] += es[m][k]*w;
    }
    _Float16* oe = sel ? ke : qe;
    #pragma unroll
    for (int m=0;m<8;m++)
        oe[(size_t)(n0+m)*128+c] = (_Float16)acc[m];
}

// ---------- phase 5: scores (fp16) = q @ k^T, single-pass fp16 MFMA ----------
__global__ __launch_bounds__(256) void k_scores(
        const _Float16* __restrict__ qe, const _Float16* __restrict__ ke,
        _Float16* __restrict__ scores){
    __shared__ float tl[4][16][36];
    int bx = blockIdx.x & 63;        // col block (64 cols)
    int by = blockIdx.x >> 6;        // row block (128 rows)
    int tid = threadIdx.x;
    int w = tid >> 6, lane = tid & 63;
    int li = lane & 15, g = lane >> 4;
    int r0 = by*128 + (w>>1)*64;
    int c0 = bx*64  + (w&1)*32;

    f32x4 acc[4][2] = {};
    for (int ks=0; ks<4; ++ks){
        int kofs = ks*32 + g*8;
        f16x8 ah[4], bh[2];
        #pragma unroll
        for (int f=0; f<4; ++f)
            ah[f] = *(const f16x8*)&qe[(size_t)(r0+f*16+li)*128 + kofs];
        #pragma unroll
        for (int f=0; f<2; ++f)
            bh[f] = *(const f16x8*)&ke[(size_t)(c0+f*16+li)*128 + kofs];
        #pragma unroll
        for (int fr=0; fr<4; ++fr){
            #pragma unroll
            for (int fc=0; fc<2; ++fc){
                acc[fr][fc] = __builtin_amdgcn_mfma_f32_16x16x32_f16(ah[fr], bh[fc], acc[fr][fc], 0, 0, 0);
            }
        }
    }
    for (int fr=0; fr<4; ++fr){
        #pragma unroll
        for (int fc=0; fc<2; ++fc)
            #pragma unroll
            for (int r=0; r<4; ++r)
                tl[w][g*4+r][fc*16+li] = acc[fr][fc][r];
        __syncthreads();
        #pragma unroll
        for (int q=0; q<2; ++q){
            int row = q*8 + (lane>>3);
            int c4 = (lane&7)*4;
            float4 v;
            v.x = tl[w][row][c4+0];
            v.y = tl[w][row][c4+1];
            v.z = tl[w][row][c4+2];
            v.w = tl[w][row][c4+3];
            half4 hv = { (_Float16)v.x, (_Float16)v.y, (_Float16)v.z, (_Float16)v.w };
            *(half4*)&scores[(size_t)(r0+fr*16+row)*NN + c0 + c4] = hv;
        }
        __syncthreads();
    }
}

// ---------- phase 5b: per-row max/min/invr from fp16 scores (wave-owned rows) ----------
__global__ __launch_bounds__(256) void k_rowmm(const _Float16* __restrict__ scores,
        float* __restrict__ rowmax, float* __restrict__ rowmin, float* __restrict__ invr){
    int tid = threadIdx.x;
    int w = tid >> 6, lane = tid & 63;
    int i = blockIdx.x*4 + w;
    const _Float16* row = scores + (size_t)i*NN;
    float mx = -INFINITY, mn = INFINITY;
    for (int t=0; t<16; ++t){
        half4 hv = *(const half4*)&row[(t*64+lane)*4];
        float a = (float)hv.x, b = (float)hv.y, c = (float)hv.z, d = (float)hv.w;
        mx = fmaxf(mx, fmaxf(fmaxf(a,b), fmaxf(c,d)));
        mn = fminf(mn, fminf(fminf(a,b), fminf(c,d)));
    }
    #pragma unroll
    for (int s=1; s<64; s<<=1){
        mx = fmaxf(mx, __shfl_xor(mx, s, 64));
        mn = fminf(mn, __shfl_xor(mn, s, 64));
    }
    if (lane == 0){
        rowmax[i] = mx;
        rowmin[i] = mn;
        invr[i] = 1.f/mx;
    }
}

// ---------- phase 6: streaming conv min/max over A (fp16 scores), half4/lane ----------
__global__ __launch_bounds__(256) void k_cconv(const _Float16* __restrict__ scores,
        const float* __restrict__ invr,
        const float* __restrict__ Wcy3, const float* __restrict__ Wcx3,
        const float* __restrict__ Wcy5, const float* __restrict__ Wcx5,
        const float* __restrict__ Wcy9, const float* __restrict__ Wcx9,
        const float* __restrict__ bcy3, const float* __restrict__ bcx3,
        const float* __restrict__ bcy5, const float* __restrict__ bcx5,
        const float* __restrict__ bcy9, const float* __restrict__ bcx9,
        float* __restrict__ mnmx){
    __shared__ float smn[4], smx[4];
    int tid = threadIdx.x;
    int w = tid >> 6, lane = tid & 63;
    int strip = blockIdx.x;                       // 0..16
    int i0 = (blockIdx.y*4 + w)*19;
    int colbase = strip*248 - 4 + lane*4;
    bool lv = (colbase >= 0) && (colbase + 3 < NN);
    bool outLane = (lane >= 1) && (lane < 63) && lv;

    float wy3[3],wx3[3],wy5[5],wx5[5],wy9[9],wx9[9];
    #pragma unroll
    for (int t=0;t<3;t++){ wy3[t]=Wcy3[t]; wx3[t]=Wcx3[t]; }
    #pragma unroll
    for (int t=0;t<5;t++){ wy5[t]=Wcy5[t]; wx5[t]=Wcx5[t]; }
    #pragma unroll
    for (int t=0;t<9;t++){ wy9[t]=Wcy9[t]; wx9[t]=Wcx9[t]; }
    float bc3 = bcy3[0]+bcx3[0];
    float bc5 = bcy5[0]+bcx5[0];
    float bc9 = bcy9[0]+bcx9[0];

    float4 win[9];
    float mn = INFINITY, mx = -INFINITY;
    const int laneL = lane - 1, laneR = lane + 1;

    for (int tb = 0; tb < 3; ++tb){
        #pragma unroll
        for (int u = 0; u < 9; ++u){
            int t  = tb*9 + u;
            int ri = i0 - 4 + t;
            float4 a = make_float4(0,0,0,0);
            if (((unsigned)ri < NN) && lv){
                float iv = invr[ri];
                half4 hv = *(const half4*)&scores[(size_t)ri*NN + colbase];
                a.x = (float)hv.x*iv; a.y = (float)hv.y*iv;
                a.z = (float)hv.z*iv; a.w = (float)hv.w*iv;
            }
            win[u] = a;
            int ro = i0 + t - 8;
            if (t >= 8 && ro < NN){
                float4 ctr = win[(u+5)%9];
                float4 wl = shfl4(ctr, laneL);
                float4 wr = shfl4(ctr, laneR);
                if (outLane){
                    float cw[12] = {wl.x,wl.y,wl.z,wl.w, ctr.x,ctr.y,ctr.z,ctr.w, wr.x,wr.y,wr.z,wr.w};
                    #pragma unroll
                    for (int c=0;c<4;c++){
                        float cx9 = ((win[(u+1)%9][c]*wx9[0] + win[(u+2)%9][c]*wx9[1]) + (win[(u+3)%9][c]*wx9[2] + win[(u+4)%9][c]*wx9[3]))
                                  + ((win[(u+5)%9][c]*wx9[4] + win[(u+6)%9][c]*wx9[5]) + (win[(u+7)%9][c]*wx9[6] + win[(u+8)%9][c]*wx9[7]))
                                  + win[u][c]*wx9[8];
                        float cx5 = ((win[(u+3)%9][c]*wx5[0] + win[(u+4)%9][c]*wx5[1]) + (win[(u+5)%9][c]*wx5[2] + win[(u+6)%9][c]*wx5[3]))
                                  + win[(u+7)%9][c]*wx5[4];
                        float cx3 = (win[(u+4)%9][c]*wx3[0] + win[(u+5)%9][c]*wx3[1]) + win[(u+6)%9][c]*wx3[2];
                        float cy9 = ((cw[c+0]*wy9[0] + cw[c+1]*wy9[1]) + (cw[c+2]*wy9[2] + cw[c+3]*wy9[3]))
                                  + ((cw[c+4]*wy9[4] + cw[c+5]*wy9[5]) + (cw[c+6]*wy9[6] + cw[c+7]*wy9[7]))
                                  + cw[c+8]*wy9[8];
                        float cy5 = ((cw[c+2]*wy5[0] + cw[c+3]*wy5[1]) + (cw[c+4]*wy5[2] + cw[c+5]*wy5[3]))
                                  + cw[c+6]*wy5[4];
                        float cy3 = (cw[c+3]*wy3[0] + cw[c+4]*wy3[1]) + cw[c+5]*wy3[2];
                        float c3v = cy3+cx3+bc3, c5v = cy5+cx5+bc5, c9v = cy9+cx9+bc9;
                        mn = fminf(mn, fminf(fminf(c3v,c5v),c9v));
                        mx = fmaxf(mx, fmaxf(fmaxf(c3v,c5v),c9v));
                    }
                }
            }
        }
    }
    #pragma unroll
    for (int m=1; m<64; m<<=1){
        mn = fminf(mn, __shfl_xor(mn, m, 64));
        mx = fmaxf(mx, __shfl_xor(mx, m, 64));
    }
    if (lane == 0){ smn[w] = mn; smx[w] = mx; }
    __syncthreads();
    if (tid == 0){
        float a0 = fminf(fminf(smn[0],smn[1]), fminf(smn[2],smn[3]));
        float b0 = fmaxf(fmaxf(smx[0],smx[1]), fmaxf(smx[2],smx[3]));
        int bid = blockIdx.y*gridDim.x + blockIdx.x;
        mnmx[bid] = a0;
        mnmx[1024 + bid] = b0;
    }
}

// ---------- phase 6b: kOt[d][0:4]=sum_j k[j][d]*Ot[j], [4:8]=...*Ty[j] ----------
__global__ __launch_bounds__(256) void k_kot(const _Float16* __restrict__ ke,
        const float4* __restrict__ otp, const float* __restrict__ Ty,
        float* __restrict__ kOt){
    __shared__ float red[256][8];
    int tid = threadIdx.x;
    int d = tid & 127, jj = tid >> 7;
    float a[8] = {0,0,0,0,0,0,0,0};
    int j0 = blockIdx.x*256;
    for (int it = 0; it < 128; ++it){
        int j = j0 + it*2 + jj;
        float kv = (float)ke[(size_t)j*128 + d];
        float4 ot = otp[j];
        float4 ty = *(const float4*)&Ty[j*4];
        a[0] += kv*ot.x; a[1] += kv*ot.y; a[2] += kv*ot.z; a[3] += kv*ot.w;
        a[4] += kv*ty.x; a[5] += kv*ty.y; a[6] += kv*ty.z; a[7] += kv*ty.w;
    }
    #pragma unroll
    for (int q=0;q<8;q++) red[tid][q] = a[q];
    __syncthreads();
    if (tid < 128){
        #pragma unroll
        for (int q=0;q<8;q++){
            float s = red[tid][q] + red[tid+128][q];
            atomicAdd(&kOt[tid*8+q], s);
        }
    }
}

// ---------- phase 6c: ASd = invr*(q@kOt), Bv from q@kTy + closed-form ----------
__global__ __launch_bounds__(256) void k_asd(
        const _Float16* __restrict__ qe,
        const float* __restrict__ kOt,
        const float* __restrict__ invr, const float* __restrict__ maxd,
        const float* __restrict__ dOt, const float* __restrict__ colsum,
        const float* __restrict__ bcy3, const float* __restrict__ bcx3,
        const float* __restrict__ bcy5, const float* __restrict__ bcx5,
        const float* __restrict__ bcy9, const float* __restrict__ bcx9,
        float* __restrict__ ASdot, float* __restrict__ Bv){
    __shared__ float kst[128*8];
    int tid = threadIdx.x;
    for (int s = tid; s < 1024; s += 256) kst[s] = kOt[s];
    __syncthreads();
    int lane = tid & 63, r = tid >> 6;
    int i = blockIdx.x*4 + r;
    float a[8] = {0,0,0,0,0,0,0,0};
    #pragma unroll
    for (int dd=0; dd<2; ++dd){
        int d = lane + dd*64;
        float qv = (float)qe[(size_t)i*128 + d];
        #pragma unroll
        for (int q=0;q<8;q++) a[q] += qv * kst[d*8+q];
    }
    #pragma unroll
    for (int m=1; m<64; m<<=1){
        #pragma unroll
        for (int q=0;q<8;q++) a[q] += __shfl_xor(a[q], m, 64);
    }
    if (lane == 0){
        float iv = invr[i];
        float imv = 1.f/maxd[i];
        float bcsum = bcy3[0]+bcx3[0]+bcy5[0]+bcx5[0]+bcy9[0]+bcx9[0];
        float k = 1.f + bcsum;
        float4 cs = *(const float4*)colsum;
        float4 dv = *(const float4*)&dOt[i*4];
        float4 pa = {iv*a[0], iv*a[1], iv*a[2], iv*a[3]};
        float4 b;
        b.x = cs.x*k - imv*dv.x + iv*a[4];
        b.y = cs.y*k - imv*dv.y + iv*a[5];
        b.z = cs.z*k - imv*dv.z + iv*a[6];
        b.w = cs.w*k - imv*dv.w + iv*a[7];
        *(float4*)&ASdot[i*4] = pa;
        *(float4*)&Bv[i*4]    = b;
    }
}

// ---------- phase 6d: global min/max = conv blocks U A-range U {0,1} ----------
__global__ __launch_bounds__(256) void k_gmm(const float* __restrict__ mnmx,
        const float* __restrict__ rowmin, const float* __restrict__ rowmax,
        float* __restrict__ gmm){
    __shared__ float smn[256], smx[256];
    int tid = threadIdx.x;
    float mn = 0.f, mx = 1.f;   // oushi range is exactly [0,1]
    for (int i=tid; i<NN; i+=256){
        float q = rowmin[i] / rowmax[i];
        mn = fminf(mn, fminf(1.f, q));
        mx = fmaxf(mx, fmaxf(1.f, q));
    }
    for (int b=tid; b<918; b+=256){   // 17 x 54 blocks
        mn = fminf(mn, mnmx[b]);
        mx = fmaxf(mx, mnmx[1024+b]);
    }
    smn[tid]=mn; smx[tid]=mx; __syncthreads();
    for (int s=128;s>0;s>>=1){
        if (tid<s){ smn[tid]=fminf(smn[tid],smn[tid+s]); smx[tid]=fmaxf(smx[tid],smx[tid+s]); }
        __syncthreads();
    }
    if (tid==0){ gmm[0]=smn[0]; gmm[1]=smx[0]; }
}

// ---------- phase 7a: row-conv of ASdot + affine -> hfin ----------
__global__ void k_hfin(const float* __restrict__ ASdot, const float* __restrict__ Bv,
        const float* __restrict__ Wcx3, const float* __restrict__ Wcx5, const float* __restrict__ Wcx9,
        const float* __restrict__ gmm, const float* __restrict__ colsum,
        float* __restrict__ hfin){
    int i = blockIdx.x*256 + threadIdx.x;
    if (i >= NN) return;
    float Cx[9];
    #pragma unroll
    for (int o=-4;o<=4;o++){
        float c = Wcx9[o+4];
        if (o>=-2 && o<=2) c += Wcx5[o+2];
        if (o>=-1 && o<=1) c += Wcx3[o+1];
        Cx[o+4] = c;
    }
    float4 h = *(const float4*)&Bv[i*4];
    float4 a0 = *(const float4*)&ASdot[i*4];
    h.x += a0.x; h.y += a0.y; h.z += a0.z; h.w += a0.w;
    #pragma unroll
    for (int o=-4;o<=4;o++){
        int r = i + o;
        if ((unsigned)r < NN){
            float4 av = *(const float4*)&ASdot[r*4];
            float c = Cx[o+4];
            h.x += c*av.x; h.y += c*av.y; h.z += c*av.z; h.w += c*av.w;
        }
    }
    float mnv = gmm[0], mxv = gmm[1];
    float s = 1.f/(mxv-mnv), oa = -mnv*s;
    float4 cs = *(const float4*)colsum;
    float4 out;
    out.x = s*h.x + 5.f*oa*cs.x;
    out.y = s*h.y + 5.f*oa*cs.y;
    out.z = s*h.z + 5.f*oa*cs.z;
    out.w = s*h.w + 5.f*oa*cs.w;
    *(float4*)&hfin[i*4] = out;
}

// ---------- phase 7b: MLP head (barrier-free epilogue) ----------
__global__ __launch_bounds__(256) void k_mlp(const float* __restrict__ hfin,
        const float* __restrict__ Woff, const float* __restrict__ boff, const float* __restrict__ pw,
        const float* __restrict__ Wf1, const float* __restrict__ bf1,
        const float* __restrict__ Wf2, const float* __restrict__ bf2,
        const float* __restrict__ Wf3, const float* __restrict__ bf3,
        float* __restrict__ out){
    __shared__ float h1[8][128];
    __shared__ float h2[8][256];
    __shared__ float h3[8][256];
    int n0 = blockIdx.x*8, tid = threadIdx.x;
    float p = pw[0];
    {
        int c = tid & 127, mb = (tid>>7)*4;
        #pragma unroll
        for (int mm=0; mm<4; mm++){
            int m = mb+mm;
            float v = boff[c];
            #pragma unroll
            for (int k=0;k<4;k++) v += hfin[(n0+m)*4+k]*Woff[k*128+c];
            h1[m][c] = v>0.f ? v : p*v;
        }
    }
    __syncthreads();
    {
        int c = tid;
        float acc[8];
        #pragma unroll
        for (int m=0;m<8;m++) acc[m] = bf1[c];
        for (int k=0;k<128;k++){
            float w = Wf1[k*256+c];
            #pragma unroll
            for (int m=0;m<8;m++) acc[m] += h1[m][k]*w;
        }
        #pragma unroll
        for (int m=0;m<8;m++) h2[m][c] = acc[m]>0.f?acc[m]:0.f;
    }
    __syncthreads();
    {
        int c = tid;
        float acc[8];
        #pragma unroll
        for (int m=0;m<8;m++) acc[m] = bf2[c];
        for (int k=0;k<256;k++){
            float w = Wf2[k*256+c];
            #pragma unroll
            for (int m=0;m<8;m++) acc[m] += h2[m][k]*w;
        }
        #pragma unroll
        for (int m=0;m<8;m++) h3[m][c] = acc[m]>0.f?acc[m]:0.f;
    }
    __syncthreads();
    int w = tid >> 6, lane = tid & 63;
    #pragma unroll
    for (int mm=0; mm<2; ++mm){
        int m = w*2 + mm;
        float4 acc = {0,0,0,0};
        #pragma unroll
        for (int q=0;q<4;q++){
            int k = lane + q*64;
            float hv = h3[m][k];
            float4 w3 = *(const float4*)&Wf3[k*4];
            acc.x += hv*w3.x; acc.y += hv*w3.y; acc.z += hv*w3.z; acc.w += hv*w3.w;
        }
        #pragma unroll
        for (int s=1; s<64; s<<=1){
            acc.x += __shfl_xor(acc.x, s, 64);
            acc.y += __shfl_xor(acc.y, s, 64);
            acc.z += __shfl_xor(acc.z, s, 64);
            acc.w += __shfl_xor(acc.w, s, 64);
        }
        if (lane == 0){
            float4 o;
            o.x = acc.x + bf3[0]; o.y = acc.y + bf3[1];
            o.z = acc.z + bf3[2]; o.w = acc.w + bf3[3];
            *(float4*)&out[(n0+m)*4] = o;
        }
    }
}

// ---------- host ----------
extern "C" void kernel_launch(void* const* d_in, const int* in_sizes, int n_in,
                              void* d_out, int out_size, void* d_ws, size_t ws_size,
                              hipStream_t stream){
    const float* dx1  = (const float*)d_in[0];
    const float* dx2  = (const float*)d_in[1];
    const float* Wk   = (const float*)d_in[2];
    const float* bk   = (const float*)d_in[3];
    const float* Wg1  = (const float*)d_in[4];
    const float* bg1  = (const float*)d_in[5];
    const float* Wg2  = (const float*)d_in[6];
    const float* bg2  = (const float*)d_in[7];
    const float* Wq   = (const float*)d_in[8];
    const float* bq   = (const float*)d_in[9];
    const float* Wkey = (const float*)d_in[10];
    const float* bkey = (const float*)d_in[11];
    const float* Woff = (const float*)d_in[12];
    const float* boff = (const float*)d_in[13];
    const float* pw   = (const float*)d_in[14];
    const float* Wf1  = (const float*)d_in[15];
    const float* bf1  = (const float*)d_in[16];
    const float* Wf2  = (const float*)d_in[17];
    const float* bf2  = (const float*)d_in[18];
    const float* Wf3  = (const float*)d_in[19];
    const float* bf3  = (const float*)d_in[20];
    const float* Wcy3 = (const float*)d_in[21];
    const float* bcy3 = (const float*)d_in[22];
    const float* Wcx3 = (const float*)d_in[23];
    const float* bcx3 = (const float*)d_in[24];
    const float* Wcy5 = (const float*)d_in[25];
    const float* bcy5 = (const float*)d_in[26];
    const float* Wcx5 = (const float*)d_in[27];
    const float* bcx5 = (const float*)d_in[28];
    const float* Wcy9 = (const float*)d_in[29];
    const float* bcy9 = (const float*)d_in[30];
    const float* Wcx9 = (const float*)d_in[31];
    const float* bcx9 = (const float*)d_in[32];

    char* ws = (char*)d_ws;
    size_t off = 0;
    auto alloc = [&](size_t b)->void*{ void* p = ws + off; off += (b + 255) & ~(size_t)255; return p; };

    // --- zero-init region (one small memset) ---
    char* zbase = ws + off;
    float*    colsum    = (float*)   alloc(4*4);
    int*      cnt3      = (int*)     alloc((size_t)NN*4);
    int*      cnt5      = (int*)     alloc((size_t)NN*4);
    int*      cnt9      = (int*)     alloc((size_t)NN*4);
    int*      cur       = (int*)     alloc((size_t)3*NN*4);
    float*    kOt       = (float*)   alloc((size_t)128*8*4);
    size_t zbytes = (size_t)((ws + off) - zbase);

    // --- non-zeroed ---
    float*  x0    = (float*) alloc((size_t)NN*8*4);
    float2* pos   = (float2*)alloc((size_t)NN*8);
    float4* otp   = (float4*)alloc((size_t)NN*16);
    float*  maxd  = (float*) alloc((size_t)NN*4);
    int*    nbr   = (int*)   alloc((size_t)NN*9*4);
    int*    offc  = (int*)   alloc((size_t)3*NN*4);
    float*  dinvc = (float*) alloc((size_t)3*NN*4);
    int*    rev   = (int*)   alloc((size_t)NN*17*4);
    float*  xw    = (float*) alloc((size_t)NN*64*4);
    float*  y2    = (float*) alloc((size_t)3*NN*128*4);
    float*  emb   = (float*) alloc((size_t)NN*384*4);
    _Float16* qe  = (_Float16*)alloc((size_t)NN*128*2);
    _Float16* ke  = (_Float16*)alloc((size_t)NN*128*2);
    _Float16* scores = (_Float16*)alloc((size_t)NN*NN*2);
    float* Tyb    = (float*)alloc((size_t)NN*4*4);
    float* rowmax = (float*)alloc((size_t)NN*4);
    float* rowmin = (float*)alloc((size_t)NN*4);
    float* invr   = (float*)alloc((size_t)NN*4);
    float* dOt    = (float*)alloc((size_t)NN*4*4);
    float* ASd    = (float*)alloc((size_t)NN*4*4);
    float* Bv     = (float*)alloc((size_t)NN*4*4);
    float* mnmx   = (float*)alloc((size_t)2*1024*4);
    float* gmm    = (float*)alloc(2*4);
    float* hfin   = (float*)alloc((size_t)NN*4*4);
    (void)ws_size; (void)in_sizes; (void)n_in; (void)out_size;

    hipMemsetAsync(zbase, 0, zbytes, stream);

    k_prep<<<16,256,0,stream>>>(dx1,dx2,Wk,bk,x0,colsum,pos,otp);
    k_ty  <<<16,256,0,stream>>>(x0,Wcy3,Wcy5,Wcy9,Tyb);
    k_dist<<<NN/2,256,0,stream>>>(pos,otp,maxd,nbr,cnt3,cnt5,cnt9,dOt);
    k_scan<<<1,256,0,stream>>>(cnt3,cnt5,cnt9,offc,dinvc);
    k_fill<<<16,256,0,stream>>>(nbr,offc,cur,rev);

    k_y1  <<<NN*64/256,256,0,stream>>>(x0,Wg1,xw);
    k_h1y2<<<NN/4,256,0,stream>>>(xw,offc,cnt3,cnt5,cnt9,rev,dinvc,bg1,Wg2,y2);
    k_fin <<<NN*3,128,0,stream>>>(y2,offc,cnt3,cnt5,cnt9,rev,dinvc,bg2,emb);

    k_qk<<<NN/8,256,0,stream>>>(emb,Wq,bq,Wkey,bkey,qe,ke);
    k_scores<<<2048,256,0,stream>>>(qe,ke,scores);
    k_rowmm<<<NN/4,256,0,stream>>>(scores,rowmax,rowmin,invr);
    k_kot<<<16,256,0,stream>>>(ke,otp,Tyb,kOt);

    k_cconv<<<dim3(17,54),256,0,stream>>>(scores,invr,
        Wcy3,Wcx3,Wcy5,Wcx5,Wcy9,Wcx9,
        bcy3,bcx3,bcy5,bcx5,bcy9,bcx9, mnmx);
    k_asd<<<NN/4,256,0,stream>>>(qe,kOt,invr,maxd,dOt,colsum,
        bcy3,bcx3,bcy5,bcx5,bcy9,bcx9, ASd, Bv);
    k_gmm<<<1,256,0,stream>>>(mnmx,rowmin,rowmax,gmm);
    k_hfin<<<16,256,0,stream>>>(ASd,Bv,Wcx3,Wcx5,Wcx9,gmm,colsum,hfin);
    k_mlp<<<NN/8,256,0,stream>>>(hfin,Woff,boff,pw,Wf1,bf1,Wf2,bf2,Wf3,bf3,(float*)d_out);
}